// Round 6
// baseline (11909.157 us; speedup 1.0000x reference)
//
#include <hip/hip_runtime.h>

// ---------------------------------------------------------------------------
// GRU (2-layer, B=64, T=1024, I=256, H=512) + FC(512->256). FP32 I/O,
// bf16 MFMA internally. R9 vs R8 (8000 us gru_fused, 7.8 us/step):
//  SINGLE CHANGE: grid 128 WGs x 512 thr (2 col-tiles + 4 K-quarters = 8
//  waves per WG) with R8's proven loop body (full-register A-prefetch, gx0
//  prefetch AFTER A-loads). Purpose: clean test of the R7 shape confound.
//  Theory: per-step cost is population-dominated — (a) A-broadcast: 128->64
//  WGs/half reading the half-state halves the ~12 MB/step L3 burst;
//  (b) barrier population 128->64 arrivals/half halves straggler skew.
//  Everything else (barrier tree, epilogue, gx0_pre, fc_out) unchanged.
//  (Resubmitted in R5 — broker timeout, never measured.)
// ---------------------------------------------------------------------------

typedef __bf16 bf16x8 __attribute__((ext_vector_type(8)));
typedef float f32x16 __attribute__((ext_vector_type(16)));

// S ping-pong: [2][64 b][1024 k] bf16 (h0 | h1), fully rewritten every launch
__device__ __align__(16) unsigned short g_S[2 * 64 * 1024];
// h1 history for the FC pass: [T*B][512] bf16 = 64 MB (normal cached stores)
__device__ __align__(16) unsigned short g_h1[1024 * 64 * 512];
// gx0: [b][t][1536] f32 = 402 MB (written by gx0_pre, read by gru_fused)
__device__ __align__(16) float g_gx0[64 * 1024 * 1536];

__device__ __forceinline__ unsigned short f2b(float f) {
    unsigned u = __float_as_uint(f);
    u += 0x7fffu + ((u >> 16) & 1u);          // round to nearest even
    return (unsigned short)(u >> 16);
}
__device__ __forceinline__ unsigned int pack2(float a, float b) {
    return (unsigned)f2b(a) | ((unsigned)f2b(b) << 16);
}
// Agent-scope (cross-XCD coherent) relaxed accessors
__device__ __forceinline__ void st32(void* p, unsigned int v) {
    __hip_atomic_store((unsigned int*)p, v, __ATOMIC_RELAXED, __HIP_MEMORY_SCOPE_AGENT);
}
__device__ __forceinline__ unsigned long long ld64(const void* p) {
    return __hip_atomic_load((const unsigned long long*)p, __ATOMIC_RELAXED,
                             __HIP_MEMORY_SCOPE_AGENT);
}
__device__ __forceinline__ bf16x8 ldfrag(const unsigned short* p) {   // 16B coherent
    union { unsigned long long q[2]; bf16x8 b; } cv;
    cv.q[0] = ld64(p);
    cv.q[1] = ld64(p + 4);
    return cv.b;
}
__device__ __forceinline__ float fsig(float x)  { return 1.0f / (1.0f + __expf(-x)); }
__device__ __forceinline__ float ftanh(float x) { return 1.0f - 2.0f / (__expf(2.0f * x) + 1.0f); }

__global__ __launch_bounds__(512, 1)
void gru_fused(const float* __restrict__ xin,   // unused (ABI)
               const float* __restrict__ Wih0, const float* __restrict__ bih0,
               const float* __restrict__ Whh0, const float* __restrict__ bhh0,
               const float* __restrict__ Wih1, const float* __restrict__ bih1,
               const float* __restrict__ Whh1, const float* __restrict__ bhh1,
               const float* __restrict__ Wfc,  const float* __restrict__ bfc,
               float* __restrict__ out, unsigned int* __restrict__ bar)
{
    (void)xin; (void)Wih0; (void)Wfc; (void)bfc; (void)out;
    __shared__ float ldsC[8 * 1056];      // [8 waves][32 rows][33] = 33.8 KB

    const int th = threadIdx.x;
    const int wg = blockIdx.x;            // 128 WGs (cooperative: co-resident)
    const int bh = wg >> 6;               // batch half
    const int jh = wg & 63;               // WG within half
    const int lay = jh >> 5;              // 0 = layer 1, 1 = layer 0
    const int w  = th >> 6;               // wave 0..7
    const int tw = w >> 2;                // col-tile in WG 0..1
    const int kq = w & 3;                 // K-quarter
    const int ln = th & 63;
    const int bloc = bh * 32;
    const int ft = 2 * jh + tw;           // flat tile: [0,64)=L1, [64,128)=L0

    unsigned short* Sbuf0 = g_S;                  // [64 b][1024 k] bf16
    unsigned short* Sbuf1 = g_S + 64 * 1024;
    unsigned short* Sbuf[2] = {Sbuf0, Sbuf1};

    // per-half barrier: 8 group lines (8 arrivals each) + 1 master
    unsigned int* grp    = bar + bh * 256;
    unsigned int* master = bar + 512 + bh * 32;

    unsigned int gen = 0;
    auto gridbar = [&]() {
        __syncthreads();                  // drains vmcnt(0): sc1 stores visible
        gen++;
        if (th == 0) {
            unsigned old = __hip_atomic_fetch_add(&grp[(jh & 7) * 32], 1u,
                              __ATOMIC_RELAXED, __HIP_MEMORY_SCOPE_AGENT);
            if ((old & 7u) == 7u)         // 8th arrival of this group this gen
                __hip_atomic_fetch_add(master, 1u,
                              __ATOMIC_RELAXED, __HIP_MEMORY_SCOPE_AGENT);
            while (__hip_atomic_load(master, __ATOMIC_RELAXED,
                                     __HIP_MEMORY_SCOPE_AGENT) < gen * 8u)
                __builtin_amdgcn_s_sleep(1);
        }
        __syncthreads();
    };

    // ---------------------------------------------------------------- phase 0
    // zero both S buffers (half-local): 2 bufs x 32 rows x 512 u32 = 32768 u32
    {
        int ltid = jh * 512 + th;                  // [0, 32768)
        int buf = ltid >> 14, rem = ltid & 16383;
        int b = bloc + (rem >> 9), kp = rem & 511;
        st32(Sbuf[buf] + b * 1024 + kp * 2, 0u);
    }

    // ------------------------- preload B-fragments from GLOBAL (fp32 -> bf16)
    // tile = 32 cols = 4 gate types x 8 units; col nl = ty*8 + p.
    // L1 (lay=0): K=1024: [0,512)=h0 (Wih1), [512,1024)=h1 (Whh1); 16 frags.
    // L0 (lay=1): K=512: h0 (Whh0); ty==2 (n_x) zero (lives in gx0); 8 frags.
    bf16x8 breg[16];
    {
        const int nl = ln & 31, ty = nl >> 3, p = nl & 7;
        const int u = (lay ? (ft - 64) : ft) * 8 + p;
        const int kh = (ln >> 5) << 3;
        if (lay == 0) {
            #pragma unroll
            for (int ks = 0; ks < 16; ++ks) {
                const int k = kq * 256 + ks * 16 + kh;
                const float* src = nullptr;
                if (k < 512) {
                    if (ty != 3) src = Wih1 + (u + (ty == 1 ? 512 : (ty == 2 ? 1024 : 0))) * 512 + k;
                } else {
                    if (ty != 2) src = Whh1 + (u + (ty == 1 ? 512 : (ty == 3 ? 1024 : 0))) * 512 + (k - 512);
                }
                bf16x8 z;
                #pragma unroll
                for (int j = 0; j < 8; ++j) z[j] = (__bf16)0.0f;
                if (src) {
                    #pragma unroll
                    for (int j = 0; j < 8; ++j) z[j] = (__bf16)src[j];
                }
                breg[ks] = z;
            }
        } else {
            #pragma unroll
            for (int ks = 0; ks < 8; ++ks) {
                const int k = kq * 128 + ks * 16 + kh;     // < 512
                const float* src = nullptr;
                if (ty != 2) src = Whh0 + (u + (ty == 1 ? 512 : (ty == 3 ? 1024 : 0))) * 512 + k;
                bf16x8 z;
                #pragma unroll
                for (int j = 0; j < 8; ++j) z[j] = (__bf16)0.0f;
                if (src) {
                    #pragma unroll
                    for (int j = 0; j < 8; ++j) z[j] = (__bf16)src[j];
                }
                breg[ks] = z;
            }
        }
    }

    // ---------------- epilogue roles: th<256 = 2 tiles x (32 rows x 4 pairs)
    const int tpw = th >> 7;              // epilogue tile (valid for th<256)
    const int ebl = th & 31;              // batch row within half
    const int eq  = (th >> 5) & 3;        // unit-pair within tile
    const int eft = 2 * jh + (tpw & 1);
    const int u0  = (lay ? (eft - 64) : eft) * 8 + 2 * eq;
    const int eb  = bloc + ebl;
    float ebs[2][4] = {{0,0,0,0},{0,0,0,0}};
    if (th < 256) {
        const float* bi  = lay ? bih0 : bih1;
        const float* bhp = lay ? bhh0 : bhh1;
        #pragma unroll
        for (int s = 0; s < 2; ++s) {
            int u = u0 + s;
            ebs[s][0] = bi[u]        + bhp[u];
            ebs[s][1] = bi[512 + u]  + bhp[512 + u];
            ebs[s][2] = bi[1024 + u];
            ebs[s][3] = bhp[1024 + u];
        }
    }
    float hprev[2][2] = {{0.f, 0.f}, {0.f, 0.f}};   // [unit][parity] fp32 state

    // gx0 double buffer (L0 epilogue threads): gxc consumed this iter (row t+1),
    // gxn loaded this iter AFTER A-loads (row t+2), rotated at iter end.
    const float* gbase = g_gx0 + (size_t)eb * 1024 * 1536 + u0;
    float2 gxc[3] = {{0,0},{0,0},{0,0}};
    float2 gxn[3] = {{0,0},{0,0},{0,0}};
    if (lay == 1 && th < 256) {
        gxc[0] = *(const float2*)(gbase);            // row 0 (iter t=-1)
        gxc[1] = *(const float2*)(gbase + 512);
        gxc[2] = *(const float2*)(gbase + 1024);
    }

    gridbar();   // phase-0 S visible half-wide

    // ------------------------------------------------------------- time loop
    for (int t = -1; t < 1024; ++t) {
        const unsigned short* Sc = Sbuf[(t + 1) & 1];
        unsigned short* Sn       = Sbuf[t & 1];

        // ---- GEMM: load ALL A-fragments first (one exposed L3 latency), ----
        // ---- then gx0 prefetch (younger in vmcnt order), then MFMA chain ----
        bf16x8 af[16];
        const unsigned short* arow = Sc + (bloc + (ln & 31)) * 1024 + ((ln >> 5) << 3);
        if (lay == 0) {
            const int kb = kq * 256;
            #pragma unroll
            for (int ks = 0; ks < 16; ++ks) af[ks] = ldfrag(arow + kb + ks * 16);
        } else {
            const int kb = kq * 128;
            #pragma unroll
            for (int ks = 0; ks < 8; ++ks) af[ks] = ldfrag(arow + kb + ks * 16);
        }
        if (lay == 1 && th < 256) {       // prefetch gx0 row t+2 (consumed next iter)
            const int tt2 = (t + 2 < 1024) ? (t + 2) : 1023;
            const float* g2 = gbase + (size_t)tt2 * 1536;
            gxn[0] = *(const float2*)(g2);
            gxn[1] = *(const float2*)(g2 + 512);
            gxn[2] = *(const float2*)(g2 + 1024);
        }
        f32x16 acc;
        #pragma unroll
        for (int i = 0; i < 16; ++i) acc[i] = 0.0f;
        if (lay == 0) {
            #pragma unroll
            for (int ks = 0; ks < 16; ++ks)
                acc = __builtin_amdgcn_mfma_f32_32x32x16_bf16(af[ks], breg[ks], acc, 0, 0, 0);
        } else {
            #pragma unroll
            for (int ks = 0; ks < 8; ++ks)
                acc = __builtin_amdgcn_mfma_f32_32x32x16_bf16(af[ks], breg[ks], acc, 0, 0, 0);
        }
        {   // partials -> LDS  (C: col=lane&31, row=(r&3)+8*(r>>2)+4*(lane>>5))
            const int col = ln & 31, rbase = (ln >> 5) << 2;
            #pragma unroll
            for (int r = 0; r < 16; ++r) {
                int row = (r & 3) + ((r >> 2) << 3) + rbase;
                ldsC[w * 1056 + row * 33 + col] = acc[r];
            }
        }
        __syncthreads();

        if (th < 256) {   // fused gate epilogue: 2 units of tile tpw per thread
            float d[2][4];
            #pragma unroll
            for (int s = 0; s < 2; ++s)
                #pragma unroll
                for (int g = 0; g < 4; ++g) d[s][g] = 0.0f;
            #pragma unroll
            for (int wq = 0; wq < 4; ++wq) {
                const float* Cw = ldsC + (tpw * 4 + wq) * 1056 + ebl * 33 + 2 * eq;
                #pragma unroll
                for (int s = 0; s < 2; ++s)
                    #pragma unroll
                    for (int g = 0; g < 4; ++g)
                        d[s][g] += Cw[g * 8 + s];
            }
            if (lay == 1) {       // add precomputed x-gates (r, z, n_x)
                d[0][0] += gxc[0].x; d[1][0] += gxc[0].y;
                d[0][1] += gxc[1].x; d[1][1] += gxc[1].y;
                d[0][2] += gxc[2].x; d[1][2] += gxc[2].y;
            }
            float hn[2];
            #pragma unroll
            for (int s = 0; s < 2; ++s) {
                float rg = fsig(d[s][0] + ebs[s][0]);
                float zg = fsig(d[s][1] + ebs[s][1]);
                float ng = ftanh((d[s][2] + ebs[s][2]) + rg * (d[s][3] + ebs[s][3]));
                float hold = hprev[s][(t + 1) & 1];
                hn[s] = ng + zg * (hold - ng);
            }
            if (lay == 1) {                        // layer 0 -> h0(t+1)
                hprev[0][t & 1] = hn[0]; hprev[1][t & 1] = hn[1];
                st32(Sn + eb * 1024 + u0, pack2(hn[0], hn[1]));
            } else if (t >= 0) {                   // layer 1 -> h1(t)
                hprev[0][t & 1] = hn[0]; hprev[1][t & 1] = hn[1];
                unsigned pk = pack2(hn[0], hn[1]);
                st32(Sn + eb * 1024 + 512 + u0, pk);
                // h1 history (normal cached store; visible at kernel end)
                *(unsigned int*)(g_h1 + ((unsigned)t * 64 + eb) * 512 + u0) = pk;
            }
        }
        // rotate gx0 double buffer
        gxc[0] = gxn[0]; gxc[1] = gxn[1]; gxc[2] = gxn[2];

        gridbar();
    }
}

// ---------------------------------------------------------------------------
// gx0_pre: g_gx0[65536][1536] = x[65536][256] @ Wih0^T (f32 out, bf16 MFMA).
// 512 WGs x 4 waves; wave = m-tile (32 rows); A held in regs, loops 48 n-tiles.
// ---------------------------------------------------------------------------
__global__ __launch_bounds__(256, 1)
void gx0_pre(const float* __restrict__ xin, const float* __restrict__ Wih0)
{
    const int th = threadIdx.x;
    const int ln = th & 63;
    const int v  = th >> 6;
    const int W  = blockIdx.x * 4 + v;        // m-tile [0, 2048)
    const int kh = (ln >> 5) << 3;
    const int cl = ln & 31;

    bf16x8 areg[16];
    {
        const float* xr = xin + ((size_t)W * 32 + cl) * 256 + kh;
        #pragma unroll
        for (int ks = 0; ks < 16; ++ks) {
            const float* s = xr + ks * 16;
            bf16x8 z;
            #pragma unroll
            for (int j = 0; j < 8; ++j) z[j] = (__bf16)s[j];
            areg[ks] = z;
        }
    }

    for (int nt = 0; nt < 48; ++nt) {
        f32x16 acc;
        #pragma unroll
        for (int q = 0; q < 16; ++q) acc[q] = 0.0f;
        const float* wb = Wih0 + (size_t)(nt * 32 + cl) * 256 + kh;
        #pragma unroll
        for (int ks = 0; ks < 16; ++ks) {
            const float* s = wb + ks * 16;
            bf16x8 z;
            #pragma unroll
            for (int j = 0; j < 8; ++j) z[j] = (__bf16)s[j];
            acc = __builtin_amdgcn_mfma_f32_32x32x16_bf16(areg[ks], z, acc, 0, 0, 0);
        }
        const int rb = (ln >> 5) << 2;
        #pragma unroll
        for (int r = 0; r < 16; ++r) {
            int rr = (r & 3) + ((r >> 2) << 3) + rb;
            g_gx0[((size_t)W * 32 + rr) * 1536 + nt * 32 + cl] = acc[r];
        }
    }
}

// ---------------------------------------------------------------------------
// FC pass: out[65536][256] = g_h1[65536][512] @ Wfc^T + bfc. (unchanged)
// ---------------------------------------------------------------------------
__global__ __launch_bounds__(256, 1)
void fc_out(const float* __restrict__ Wfc, const float* __restrict__ bfc,
            float* __restrict__ out)
{
    const int th = threadIdx.x;
    const int ln = th & 63;
    const int v  = th >> 6;
    const int w  = blockIdx.x * 4 + v;    // [0, 1024)
    const int ntile = w & 7;
    const int mbase = w >> 3;             // [0, 128)
    const int kh = (ln >> 5) << 3;
    const int col = ln & 31;

    bf16x8 fb[32];
    {
        const int n = ntile * 32 + col;
        #pragma unroll
        for (int ks = 0; ks < 32; ++ks) {
            const float* src = Wfc + n * 512 + ks * 16 + kh;
            bf16x8 z;
            #pragma unroll
            for (int j = 0; j < 8; ++j) z[j] = (__bf16)src[j];
            fb[ks] = z;
        }
    }
    const float bias = bfc[ntile * 32 + col];

    for (int i = 0; i < 16; ++i) {
        const int mt = mbase + i * 128;   // m-tile [0, 2048)
        const unsigned short* ar = g_h1 + ((unsigned)(mt * 32 + col)) * 512 + kh;
        f32x16 acc;
        #pragma unroll
        for (int q = 0; q < 16; ++q) acc[q] = 0.0f;
        #pragma unroll
        for (int ks = 0; ks < 32; ++ks) {
            bf16x8 af = *(const bf16x8*)(ar + ks * 16);
            acc = __builtin_amdgcn_mfma_f32_32x32x16_bf16(af, fb[ks], acc, 0, 0, 0);
        }
        const int rb = (ln >> 5) << 2;
        #pragma unroll
        for (int r = 0; r < 16; ++r) {
            int row = (r & 3) + ((r >> 2) << 3) + rb;
            out[((unsigned)(mt * 32 + row)) * 256 + ntile * 32 + col] = acc[r] + bias;
        }
    }
}

extern "C" void kernel_launch(void* const* d_in, const int* in_sizes, int n_in,
                              void* d_out, int out_size, void* d_ws, size_t ws_size,
                              hipStream_t stream) {
    (void)in_sizes; (void)n_in; (void)out_size; (void)ws_size;
    hipMemsetAsync(d_ws, 0, 4096, stream);   // barrier counters (monotonic per launch)
    const float* xin  = (const float*)d_in[0];
    const float* Wih0 = (const float*)d_in[1];
    const float* bih0 = (const float*)d_in[2];
    const float* Whh0 = (const float*)d_in[3];
    const float* bhh0 = (const float*)d_in[4];
    const float* Wih1 = (const float*)d_in[5];
    const float* bih1 = (const float*)d_in[6];
    const float* Whh1 = (const float*)d_in[7];
    const float* bhh1 = (const float*)d_in[8];
    const float* Wfc  = (const float*)d_in[9];
    const float* bfc  = (const float*)d_in[10];
    float* outp = (float*)d_out;
    unsigned int* barp = (unsigned int*)d_ws;

    hipLaunchKernelGGL(gx0_pre, dim3(512), dim3(256), 0, stream, xin, Wih0);

    void* args[] = {&xin, &Wih0, &bih0, &Whh0, &bhh0, &Wih1, &bih1,
                    &Whh1, &bhh1, &Wfc, &bfc, &outp, &barp};
    hipLaunchCooperativeKernel((void*)gru_fused, dim3(128), dim3(512),
                               args, 0, stream);
    hipLaunchKernelGGL(fc_out, dim3(256), dim3(256), 0, stream,
                       Wfc, bfc, outp);
}

// Round 7
// 6314.026 us; speedup vs baseline: 1.8861x; 1.8861x over previous
//
#include <hip/hip_runtime.h>

// ---------------------------------------------------------------------------
// GRU (2-layer, B=64, T=1024, I=256, H=512) + FC(512->256). FP32 I/O,
// bf16 MFMA internally. R10 vs R8 (8000 us gru_fused, best; R7/R9 both
// showed 512-thr shape costs +3.3 us/step -> per-CU scattered-load bound):
//  SINGLE CHANGE: per-wave coalesced LDS staging of the A (state) quarter.
//  Old: per-frag ld64 with lane=row (stride 2KB) -> ~32 line-requests per
//  instruction to the L3 coherence point (sc1 bypasses L1/L2).
//  New: lane=k-offset staging (64 lanes x 16B = 2 row-quarters per instr,
//  fully coalesced), ds_write to padded per-wave LDS (row stride 65/33
//  ulongs == 2 banks/row -> 2-way ~free), MFMA frags via 2x ds_read_b64.
//  Same bytes, same coherence, no extra barriers (wave-private staging).
//  Frame: 256 WGs x 256 thr, barrier tree, gx0, epilogue, fc_out unchanged.
// ---------------------------------------------------------------------------

typedef __bf16 bf16x8 __attribute__((ext_vector_type(8)));
typedef float f32x16 __attribute__((ext_vector_type(16)));

// S ping-pong: [2][64 b][1024 k] bf16 (h0 | h1), fully rewritten every launch
__device__ __align__(16) unsigned short g_S[2 * 64 * 1024];
// h1 history for the FC pass: [T*B][512] bf16 = 64 MB (normal cached stores)
__device__ __align__(16) unsigned short g_h1[1024 * 64 * 512];
// gx0: [b][t][1536] f32 = 402 MB (written by gx0_pre, read by gru_fused)
__device__ __align__(16) float g_gx0[64 * 1024 * 1536];

__device__ __forceinline__ unsigned short f2b(float f) {
    unsigned u = __float_as_uint(f);
    u += 0x7fffu + ((u >> 16) & 1u);          // round to nearest even
    return (unsigned short)(u >> 16);
}
__device__ __forceinline__ unsigned int pack2(float a, float b) {
    return (unsigned)f2b(a) | ((unsigned)f2b(b) << 16);
}
// Agent-scope (cross-XCD coherent) relaxed accessors
__device__ __forceinline__ void st32(void* p, unsigned int v) {
    __hip_atomic_store((unsigned int*)p, v, __ATOMIC_RELAXED, __HIP_MEMORY_SCOPE_AGENT);
}
__device__ __forceinline__ unsigned long long ld64(const void* p) {
    return __hip_atomic_load((const unsigned long long*)p, __ATOMIC_RELAXED,
                             __HIP_MEMORY_SCOPE_AGENT);
}
__device__ __forceinline__ bf16x8 ldfrag(const unsigned short* p) {   // 16B coherent
    union { unsigned long long q[2]; bf16x8 b; } cv;
    cv.q[0] = ld64(p);
    cv.q[1] = ld64(p + 4);
    return cv.b;
}
__device__ __forceinline__ float fsig(float x)  { return 1.0f / (1.0f + __expf(-x)); }
__device__ __forceinline__ float ftanh(float x) { return 1.0f - 2.0f / (__expf(2.0f * x) + 1.0f); }

__global__ __launch_bounds__(256, 1)
void gru_fused(const float* __restrict__ xin,   // unused (ABI)
               const float* __restrict__ Wih0, const float* __restrict__ bih0,
               const float* __restrict__ Whh0, const float* __restrict__ bhh0,
               const float* __restrict__ Wih1, const float* __restrict__ bih1,
               const float* __restrict__ Whh1, const float* __restrict__ bhh1,
               const float* __restrict__ Wfc,  const float* __restrict__ bfc,
               float* __restrict__ out, unsigned int* __restrict__ bar)
{
    (void)xin; (void)Wih0; (void)Wfc; (void)bfc; (void)out;
    // per-wave A staging: [4 waves][32 rows][65 ulong (520 B: 512 + 8 pad)]
    // pad -> bank advance 2/row -> 2-way (free) on the 32-row column reads.
    __shared__ unsigned long long aS[4 * 2080];   // 66.6 KB
    __shared__ float ldsC[4224];                  // [4 waves][32 rows][33]

    const int th = threadIdx.x;
    const int wg = blockIdx.x;            // 256 WGs (cooperative: co-resident)
    const int bh = wg >> 7;               // batch half
    const int r_ = wg & 127;
    const int lay = r_ >> 6;              // 0 = layer 1, 1 = layer 0
    const int cg  = r_ & 63;              // column group: units 8cg..8cg+7
    const int kq = th >> 6;               // wave = K-split
    const int ln = th & 63;
    const int bloc = bh * 32;

    unsigned short* Sbuf0 = g_S;                  // [64 b][1024 k] bf16
    unsigned short* Sbuf1 = g_S + 64 * 1024;
    unsigned short* Sbuf[2] = {Sbuf0, Sbuf1};

    // per-half barrier: 8 group lines (16 arrivals each) + 1 master
    unsigned int* grp    = bar + bh * 256;
    unsigned int* master = bar + 512 + bh * 32;

    unsigned int gen = 0;
    auto gridbar = [&]() {
        __syncthreads();                  // drains vmcnt(0): sc1 stores visible
        gen++;
        if (th == 0) {
            unsigned old = __hip_atomic_fetch_add(&grp[(r_ & 7) * 32], 1u,
                              __ATOMIC_RELAXED, __HIP_MEMORY_SCOPE_AGENT);
            if ((old & 15u) == 15u)       // 16th arrival of this group this gen
                __hip_atomic_fetch_add(master, 1u,
                              __ATOMIC_RELAXED, __HIP_MEMORY_SCOPE_AGENT);
            while (__hip_atomic_load(master, __ATOMIC_RELAXED,
                                     __HIP_MEMORY_SCOPE_AGENT) < gen * 8u)
                __builtin_amdgcn_s_sleep(1);
        }
        __syncthreads();
    };

    // ---------------------------------------------------------------- phase 0
    // zero both S buffers (half-local): 2 bufs x 32 rows x 512 u32 = 32768 u32
    {
        int ltid = r_ * 256 + th;                  // [0, 32768)
        int buf = ltid >> 14, rem = ltid & 16383;
        int b = bloc + (rem >> 9), kp = rem & 511;
        st32(Sbuf[buf] + b * 1024 + kp * 2, 0u);
    }

    // ------------------------- preload B-fragments from GLOBAL (fp32 -> bf16)
    // tile = 32 cols = 4 gate types x 8 units; col nl = ty*8 + p.
    // L1 (lay=0): K=1024: [0,512)=h0 (Wih1), [512,1024)=h1 (Whh1); 16 frags.
    // L0 (lay=1): K=512: h0 (Whh0); ty==2 (n_x) zero (lives in gx0); 8 frags.
    bf16x8 breg[16];
    {
        const int nl = ln & 31, ty = nl >> 3, p = nl & 7;
        const int u = cg * 8 + p;
        const int kh = (ln >> 5) << 3;
        if (lay == 0) {
            #pragma unroll
            for (int ks = 0; ks < 16; ++ks) {
                const int k = kq * 256 + ks * 16 + kh;
                const float* src = nullptr;
                if (k < 512) {
                    if (ty != 3) src = Wih1 + (u + (ty == 1 ? 512 : (ty == 2 ? 1024 : 0))) * 512 + k;
                } else {
                    if (ty != 2) src = Whh1 + (u + (ty == 1 ? 512 : (ty == 3 ? 1024 : 0))) * 512 + (k - 512);
                }
                bf16x8 z;
                #pragma unroll
                for (int j = 0; j < 8; ++j) z[j] = (__bf16)0.0f;
                if (src) {
                    #pragma unroll
                    for (int j = 0; j < 8; ++j) z[j] = (__bf16)src[j];
                }
                breg[ks] = z;
            }
        } else {
            #pragma unroll
            for (int ks = 0; ks < 8; ++ks) {
                const int k = kq * 128 + ks * 16 + kh;     // < 512
                const float* src = nullptr;
                if (ty != 2) src = Whh0 + (u + (ty == 1 ? 512 : (ty == 3 ? 1024 : 0))) * 512 + k;
                bf16x8 z;
                #pragma unroll
                for (int j = 0; j < 8; ++j) z[j] = (__bf16)0.0f;
                if (src) {
                    #pragma unroll
                    for (int j = 0; j < 8; ++j) z[j] = (__bf16)src[j];
                }
                breg[ks] = z;
            }
        }
    }

    // -------------------- epilogue roles: 128 threads x 2 adjacent units each
    const int ebl = th & 31;              // batch row within half
    const int eq  = (th >> 5) & 3;        // unit-pair within tile
    const int u0 = cg * 8 + 2 * eq;
    const int eb = bloc + ebl;
    float ebs[2][4];
    {
        const float* bi  = lay ? bih0 : bih1;
        const float* bhp = lay ? bhh0 : bhh1;
        #pragma unroll
        for (int s = 0; s < 2; ++s) {
            int u = u0 + s;
            ebs[s][0] = bi[u]        + bhp[u];
            ebs[s][1] = bi[512 + u]  + bhp[512 + u];
            ebs[s][2] = bi[1024 + u];
            ebs[s][3] = bhp[1024 + u];
        }
    }
    float hprev[2][2] = {{0.f, 0.f}, {0.f, 0.f}};   // [unit][parity] fp32 state

    // gx0 double buffer (L0 epilogue threads): gxc consumed this iter (row t+1),
    // gxn loaded this iter AFTER staging loads, rotated at iter end.
    const float* gbase = g_gx0 + (size_t)eb * 1024 * 1536 + u0;
    float2 gxc[3] = {{0,0},{0,0},{0,0}};
    float2 gxn[3] = {{0,0},{0,0},{0,0}};
    if (lay == 1 && th < 128) {
        gxc[0] = *(const float2*)(gbase);            // row 0 (iter t=-1)
        gxc[1] = *(const float2*)(gbase + 512);
        gxc[2] = *(const float2*)(gbase + 1024);
    }

    unsigned long long* aW = aS + kq * 2080;         // this wave's staging block

    gridbar();   // phase-0 S visible half-wide

    // ------------------------------------------------------------- time loop
    for (int t = -1; t < 1024; ++t) {
        const unsigned short* Sc = Sbuf[(t + 1) & 1];
        unsigned short* Sn       = Sbuf[t & 1];

        // ---- stage this wave's A-quarter, COALESCED (lane = k-offset) ----
        // L1: quarter = 32 rows x 512 B; iter i covers rows 2i,2i+1
        //     (64 lanes x 16 B = 1 KB). L0: 32 rows x 256 B; rows 4i..4i+3.
        unsigned long long tq[32];
        if (lay == 0) {
            const unsigned short* sb = Sc + bloc * 1024 + kq * 256 + (ln & 31) * 8;
            #pragma unroll
            for (int i = 0; i < 16; ++i) {
                const unsigned short* p = sb + (2 * i + (ln >> 5)) * 1024;
                tq[2 * i]     = ld64(p);
                tq[2 * i + 1] = ld64(p + 4);
            }
        } else {
            const unsigned short* sb = Sc + bloc * 1024 + kq * 128 + (ln & 15) * 8;
            #pragma unroll
            for (int i = 0; i < 8; ++i) {
                const unsigned short* p = sb + (4 * i + (ln >> 4)) * 1024;
                tq[2 * i]     = ld64(p);
                tq[2 * i + 1] = ld64(p + 4);
            }
        }
        if (lay == 1 && th < 128) {       // prefetch gx0 row t+2 (consumed next iter)
            const int tt2 = (t + 2 < 1024) ? (t + 2) : 1023;
            const float* g2 = gbase + (size_t)tt2 * 1536;
            gxn[0] = *(const float2*)(g2);
            gxn[1] = *(const float2*)(g2 + 512);
            gxn[2] = *(const float2*)(g2 + 1024);
        }
        // ---- ds_write staged quarter (row stride 65/33 ulongs, +pad) ----
        if (lay == 0) {
            #pragma unroll
            for (int i = 0; i < 16; ++i) {
                const int idx = (2 * i + (ln >> 5)) * 65 + (ln & 31) * 2;
                aW[idx]     = tq[2 * i];
                aW[idx + 1] = tq[2 * i + 1];
            }
        } else {
            #pragma unroll
            for (int i = 0; i < 8; ++i) {
                const int idx = (4 * i + (ln >> 4)) * 33 + (ln & 15) * 2;
                aW[idx]     = tq[2 * i];
                aW[idx + 1] = tq[2 * i + 1];
            }
        }
        // ---- MFMA chain: fragments from LDS (lane = row, 2x ds_read_b64) ----
        f32x16 acc;
        #pragma unroll
        for (int i = 0; i < 16; ++i) acc[i] = 0.0f;
        if (lay == 0) {
            const unsigned long long* rb = aW + (ln & 31) * 65 + (ln >> 5) * 2;
            #pragma unroll
            for (int ks = 0; ks < 16; ++ks) {
                union { unsigned long long q[2]; bf16x8 b; } fv;
                fv.q[0] = rb[ks * 4];
                fv.q[1] = rb[ks * 4 + 1];
                acc = __builtin_amdgcn_mfma_f32_32x32x16_bf16(fv.b, breg[ks], acc, 0, 0, 0);
            }
        } else {
            const unsigned long long* rb = aW + (ln & 31) * 33 + (ln >> 5) * 2;
            #pragma unroll
            for (int ks = 0; ks < 8; ++ks) {
                union { unsigned long long q[2]; bf16x8 b; } fv;
                fv.q[0] = rb[ks * 4];
                fv.q[1] = rb[ks * 4 + 1];
                acc = __builtin_amdgcn_mfma_f32_32x32x16_bf16(fv.b, breg[ks], acc, 0, 0, 0);
            }
        }
        {   // partials -> LDS  (C: col=lane&31, row=(r&3)+8*(r>>2)+4*(lane>>5))
            const int col = ln & 31, rbase = (ln >> 5) << 2;
            #pragma unroll
            for (int r = 0; r < 16; ++r) {
                int row = (r & 3) + ((r >> 2) << 3) + rbase;
                ldsC[(kq * 32 + row) * 33 + col] = acc[r];
            }
        }
        __syncthreads();

        if (th < 128) {   // fused gate epilogue: 2 units per thread
            float d[2][4];
            #pragma unroll
            for (int s = 0; s < 2; ++s)
                #pragma unroll
                for (int g = 0; g < 4; ++g) d[s][g] = 0.0f;
            #pragma unroll
            for (int w = 0; w < 4; ++w) {
                const float* Cw = ldsC + (w * 32 + ebl) * 33 + 2 * eq;
                #pragma unroll
                for (int s = 0; s < 2; ++s)
                    #pragma unroll
                    for (int g = 0; g < 4; ++g)
                        d[s][g] += Cw[g * 8 + s];
            }
            if (lay == 1) {       // add precomputed x-gates (r, z, n_x)
                d[0][0] += gxc[0].x; d[1][0] += gxc[0].y;
                d[0][1] += gxc[1].x; d[1][1] += gxc[1].y;
                d[0][2] += gxc[2].x; d[1][2] += gxc[2].y;
            }
            float hn[2];
            #pragma unroll
            for (int s = 0; s < 2; ++s) {
                float rg = fsig(d[s][0] + ebs[s][0]);
                float zg = fsig(d[s][1] + ebs[s][1]);
                float ng = ftanh((d[s][2] + ebs[s][2]) + rg * (d[s][3] + ebs[s][3]));
                float hold = hprev[s][(t + 1) & 1];
                hn[s] = ng + zg * (hold - ng);
            }
            if (lay == 1) {                        // layer 0 -> h0(t+1)
                hprev[0][t & 1] = hn[0]; hprev[1][t & 1] = hn[1];
                st32(Sn + eb * 1024 + u0, pack2(hn[0], hn[1]));
            } else if (t >= 0) {                   // layer 1 -> h1(t)
                hprev[0][t & 1] = hn[0]; hprev[1][t & 1] = hn[1];
                unsigned pk = pack2(hn[0], hn[1]);
                st32(Sn + eb * 1024 + 512 + u0, pk);
                // h1 history (normal cached store; visible at kernel end)
                *(unsigned int*)(g_h1 + ((unsigned)t * 64 + eb) * 512 + u0) = pk;
            }
        }
        // rotate gx0 double buffer
        gxc[0] = gxn[0]; gxc[1] = gxn[1]; gxc[2] = gxn[2];

        gridbar();
    }
}

// ---------------------------------------------------------------------------
// gx0_pre: g_gx0[65536][1536] = x[65536][256] @ Wih0^T (f32 out, bf16 MFMA).
// 512 WGs x 4 waves; wave = m-tile (32 rows); A held in regs, loops 48 n-tiles.
// ---------------------------------------------------------------------------
__global__ __launch_bounds__(256, 1)
void gx0_pre(const float* __restrict__ xin, const float* __restrict__ Wih0)
{
    const int th = threadIdx.x;
    const int ln = th & 63;
    const int v  = th >> 6;
    const int W  = blockIdx.x * 4 + v;        // m-tile [0, 2048)
    const int kh = (ln >> 5) << 3;
    const int cl = ln & 31;

    bf16x8 areg[16];
    {
        const float* xr = xin + ((size_t)W * 32 + cl) * 256 + kh;
        #pragma unroll
        for (int ks = 0; ks < 16; ++ks) {
            const float* s = xr + ks * 16;
            bf16x8 z;
            #pragma unroll
            for (int j = 0; j < 8; ++j) z[j] = (__bf16)s[j];
            areg[ks] = z;
        }
    }

    for (int nt = 0; nt < 48; ++nt) {
        f32x16 acc;
        #pragma unroll
        for (int q = 0; q < 16; ++q) acc[q] = 0.0f;
        const float* wb = Wih0 + (size_t)(nt * 32 + cl) * 256 + kh;
        #pragma unroll
        for (int ks = 0; ks < 16; ++ks) {
            const float* s = wb + ks * 16;
            bf16x8 z;
            #pragma unroll
            for (int j = 0; j < 8; ++j) z[j] = (__bf16)s[j];
            acc = __builtin_amdgcn_mfma_f32_32x32x16_bf16(areg[ks], z, acc, 0, 0, 0);
        }
        const int rb = (ln >> 5) << 2;
        #pragma unroll
        for (int r = 0; r < 16; ++r) {
            int rr = (r & 3) + ((r >> 2) << 3) + rb;
            g_gx0[((size_t)W * 32 + rr) * 1536 + nt * 32 + cl] = acc[r];
        }
    }
}

// ---------------------------------------------------------------------------
// FC pass: out[65536][256] = g_h1[65536][512] @ Wfc^T + bfc. (unchanged)
// ---------------------------------------------------------------------------
__global__ __launch_bounds__(256, 1)
void fc_out(const float* __restrict__ Wfc, const float* __restrict__ bfc,
            float* __restrict__ out)
{
    const int th = threadIdx.x;
    const int ln = th & 63;
    const int v  = th >> 6;
    const int w  = blockIdx.x * 4 + v;    // [0, 1024)
    const int ntile = w & 7;
    const int mbase = w >> 3;             // [0, 128)
    const int kh = (ln >> 5) << 3;
    const int col = ln & 31;

    bf16x8 fb[32];
    {
        const int n = ntile * 32 + col;
        #pragma unroll
        for (int ks = 0; ks < 32; ++ks) {
            const float* src = Wfc + n * 512 + ks * 16 + kh;
            bf16x8 z;
            #pragma unroll
            for (int j = 0; j < 8; ++j) z[j] = (__bf16)src[j];
            fb[ks] = z;
        }
    }
    const float bias = bfc[ntile * 32 + col];

    for (int i = 0; i < 16; ++i) {
        const int mt = mbase + i * 128;   // m-tile [0, 2048)
        const unsigned short* ar = g_h1 + ((unsigned)(mt * 32 + col)) * 512 + kh;
        f32x16 acc;
        #pragma unroll
        for (int q = 0; q < 16; ++q) acc[q] = 0.0f;
        #pragma unroll
        for (int ks = 0; ks < 32; ++ks) {
            bf16x8 af = *(const bf16x8*)(ar + ks * 16);
            acc = __builtin_amdgcn_mfma_f32_32x32x16_bf16(af, fb[ks], acc, 0, 0, 0);
        }
        const int rb = (ln >> 5) << 2;
        #pragma unroll
        for (int r = 0; r < 16; ++r) {
            int row = (r & 3) + ((r >> 2) << 3) + rb;
            out[((unsigned)(mt * 32 + row)) * 256 + ntile * 32 + col] = acc[r] + bias;
        }
    }
}

extern "C" void kernel_launch(void* const* d_in, const int* in_sizes, int n_in,
                              void* d_out, int out_size, void* d_ws, size_t ws_size,
                              hipStream_t stream) {
    (void)in_sizes; (void)n_in; (void)out_size; (void)ws_size;
    hipMemsetAsync(d_ws, 0, 4096, stream);   // barrier counters (monotonic per launch)
    const float* xin  = (const float*)d_in[0];
    const float* Wih0 = (const float*)d_in[1];
    const float* bih0 = (const float*)d_in[2];
    const float* Whh0 = (const float*)d_in[3];
    const float* bhh0 = (const float*)d_in[4];
    const float* Wih1 = (const float*)d_in[5];
    const float* bih1 = (const float*)d_in[6];
    const float* Whh1 = (const float*)d_in[7];
    const float* bhh1 = (const float*)d_in[8];
    const float* Wfc  = (const float*)d_in[9];
    const float* bfc  = (const float*)d_in[10];
    float* outp = (float*)d_out;
    unsigned int* barp = (unsigned int*)d_ws;

    hipLaunchKernelGGL(gx0_pre, dim3(512), dim3(256), 0, stream, xin, Wih0);

    void* args[] = {&xin, &Wih0, &bih0, &Whh0, &bhh0, &Wih1, &bih1,
                    &Whh1, &bhh1, &Wfc, &bfc, &outp, &barp};
    hipLaunchCooperativeKernel((void*)gru_fused, dim3(256), dim3(256),
                               args, 0, stream);
    hipLaunchKernelGGL(fc_out, dim3(256), dim3(256), 0, stream,
                       Wfc, bfc, outp);
}

// Round 9
// 6256.209 us; speedup vs baseline: 1.9036x; 1.0092x over previous
//
#include <hip/hip_runtime.h>

// ---------------------------------------------------------------------------
// GRU (2-layer, B=64, T=1024, I=256, H=512) + FC(512->256). FP32 I/O,
// bf16 MFMA internally. R12 = R10 (last-good, 5649 us) + ONE change:
//  De-interleaved LDS staging layout (even ulongs -> slots 0..half-1, odd ->
//  slots half..2*half-1; half=32 L1 / 16 L0). R10's 16B/lane pattern hit 8
//  lane-slots/bank (2x conflict, SQ_LDS_BANK_CONFLICT=1.008e8); new layout
//  is exactly the 4-slot wave64 b64 minimum on BOTH ds_write and ds_read.
//  R11's consolidation is fully reverted (failed correctness; suspected
//  silent cooperative-launch rejection at LDS=100,352 B > proven 83,456 B).
// ---------------------------------------------------------------------------

typedef __bf16 bf16x8 __attribute__((ext_vector_type(8)));
typedef float f32x16 __attribute__((ext_vector_type(16)));

// S ping-pong: [2][64 b][1024 k] bf16 (h0 | h1), fully rewritten every launch
__device__ __align__(16) unsigned short g_S[2 * 64 * 1024];
// h1 history for the FC pass: [T*B][512] bf16 = 64 MB (normal cached stores)
__device__ __align__(16) unsigned short g_h1[1024 * 64 * 512];
// gx0: [b][t][1536] f32 = 402 MB (written by gx0_pre, read by gru_fused)
__device__ __align__(16) float g_gx0[64 * 1024 * 1536];

__device__ __forceinline__ unsigned short f2b(float f) {
    unsigned u = __float_as_uint(f);
    u += 0x7fffu + ((u >> 16) & 1u);          // round to nearest even
    return (unsigned short)(u >> 16);
}
__device__ __forceinline__ unsigned int pack2(float a, float b) {
    return (unsigned)f2b(a) | ((unsigned)f2b(b) << 16);
}
// Agent-scope (cross-XCD coherent) relaxed accessors
__device__ __forceinline__ void st32(void* p, unsigned int v) {
    __hip_atomic_store((unsigned int*)p, v, __ATOMIC_RELAXED, __HIP_MEMORY_SCOPE_AGENT);
}
__device__ __forceinline__ unsigned long long ld64(const void* p) {
    return __hip_atomic_load((const unsigned long long*)p, __ATOMIC_RELAXED,
                             __HIP_MEMORY_SCOPE_AGENT);
}
__device__ __forceinline__ float fsig(float x)  { return 1.0f / (1.0f + __expf(-x)); }
__device__ __forceinline__ float ftanh(float x) { return 1.0f - 2.0f / (__expf(2.0f * x) + 1.0f); }

__global__ __launch_bounds__(256, 1)
void gru_fused(const float* __restrict__ xin,   // unused (ABI)
               const float* __restrict__ Wih0, const float* __restrict__ bih0,
               const float* __restrict__ Whh0, const float* __restrict__ bhh0,
               const float* __restrict__ Wih1, const float* __restrict__ bih1,
               const float* __restrict__ Whh1, const float* __restrict__ bhh1,
               const float* __restrict__ Wfc,  const float* __restrict__ bfc,
               float* __restrict__ out, unsigned int* __restrict__ bar)
{
    (void)xin; (void)Wih0; (void)Wfc; (void)bfc; (void)out;
    // per-wave A staging: [4 waves][32 rows][65 ulong], de-interleaved slots.
    __shared__ unsigned long long aS[4 * 2080];   // 66.6 KB
    __shared__ float ldsC[4224];                  // [4 waves][32 rows][33]

    const int th = threadIdx.x;
    const int wg = blockIdx.x;            // 256 WGs (cooperative: co-resident)
    const int bh = wg >> 7;               // batch half
    const int r_ = wg & 127;
    const int lay = r_ >> 6;              // 0 = layer 1, 1 = layer 0
    const int cg  = r_ & 63;              // column group: units 8cg..8cg+7
    const int kq = th >> 6;               // wave = K-split
    const int ln = th & 63;
    const int bloc = bh * 32;

    unsigned short* Sbuf0 = g_S;                  // [64 b][1024 k] bf16
    unsigned short* Sbuf1 = g_S + 64 * 1024;
    unsigned short* Sbuf[2] = {Sbuf0, Sbuf1};

    // per-half barrier: 8 group lines (16 arrivals each) + 1 master
    unsigned int* grp    = bar + bh * 256;
    unsigned int* master = bar + 512 + bh * 32;

    unsigned int gen = 0;
    auto gridbar = [&]() {
        __syncthreads();                  // drains vmcnt(0): sc1 stores visible
        gen++;
        if (th == 0) {
            unsigned old = __hip_atomic_fetch_add(&grp[(r_ & 7) * 32], 1u,
                              __ATOMIC_RELAXED, __HIP_MEMORY_SCOPE_AGENT);
            if ((old & 15u) == 15u)       // 16th arrival of this group this gen
                __hip_atomic_fetch_add(master, 1u,
                              __ATOMIC_RELAXED, __HIP_MEMORY_SCOPE_AGENT);
            while (__hip_atomic_load(master, __ATOMIC_RELAXED,
                                     __HIP_MEMORY_SCOPE_AGENT) < gen * 8u)
                __builtin_amdgcn_s_sleep(1);
        }
        __syncthreads();
    };

    // ---------------------------------------------------------------- phase 0
    // zero both S buffers (half-local): 2 bufs x 32 rows x 512 u32 = 32768 u32
    {
        int ltid = r_ * 256 + th;                  // [0, 32768)
        int buf = ltid >> 14, rem = ltid & 16383;
        int b = bloc + (rem >> 9), kp = rem & 511;
        st32(Sbuf[buf] + b * 1024 + kp * 2, 0u);
    }

    // ------------------------- preload B-fragments from GLOBAL (fp32 -> bf16)
    // tile = 32 cols = 4 gate types x 8 units; col nl = ty*8 + p.
    // L1 (lay=0): K=1024: [0,512)=h0 (Wih1), [512,1024)=h1 (Whh1); 16 frags.
    // L0 (lay=1): K=512: h0 (Whh0); ty==2 (n_x) zero (lives in gx0); 8 frags.
    bf16x8 breg[16];
    {
        const int nl = ln & 31, ty = nl >> 3, p = nl & 7;
        const int u = cg * 8 + p;
        const int kh = (ln >> 5) << 3;
        if (lay == 0) {
            #pragma unroll
            for (int ks = 0; ks < 16; ++ks) {
                const int k = kq * 256 + ks * 16 + kh;
                const float* src = nullptr;
                if (k < 512) {
                    if (ty != 3) src = Wih1 + (u + (ty == 1 ? 512 : (ty == 2 ? 1024 : 0))) * 512 + k;
                } else {
                    if (ty != 2) src = Whh1 + (u + (ty == 1 ? 512 : (ty == 3 ? 1024 : 0))) * 512 + (k - 512);
                }
                bf16x8 z;
                #pragma unroll
                for (int j = 0; j < 8; ++j) z[j] = (__bf16)0.0f;
                if (src) {
                    #pragma unroll
                    for (int j = 0; j < 8; ++j) z[j] = (__bf16)src[j];
                }
                breg[ks] = z;
            }
        } else {
            #pragma unroll
            for (int ks = 0; ks < 8; ++ks) {
                const int k = kq * 128 + ks * 16 + kh;     // < 512
                const float* src = nullptr;
                if (ty != 2) src = Whh0 + (u + (ty == 1 ? 512 : (ty == 3 ? 1024 : 0))) * 512 + k;
                bf16x8 z;
                #pragma unroll
                for (int j = 0; j < 8; ++j) z[j] = (__bf16)0.0f;
                if (src) {
                    #pragma unroll
                    for (int j = 0; j < 8; ++j) z[j] = (__bf16)src[j];
                }
                breg[ks] = z;
            }
        }
    }

    // -------------------- epilogue roles: 128 threads x 2 adjacent units each
    const int ebl = th & 31;              // batch row within half
    const int eq  = (th >> 5) & 3;        // unit-pair within tile
    const int u0 = cg * 8 + 2 * eq;
    const int eb = bloc + ebl;
    float ebs[2][4];
    {
        const float* bi  = lay ? bih0 : bih1;
        const float* bhp = lay ? bhh0 : bhh1;
        #pragma unroll
        for (int s = 0; s < 2; ++s) {
            int u = u0 + s;
            ebs[s][0] = bi[u]        + bhp[u];
            ebs[s][1] = bi[512 + u]  + bhp[512 + u];
            ebs[s][2] = bi[1024 + u];
            ebs[s][3] = bhp[1024 + u];
        }
    }
    float hprev[2][2] = {{0.f, 0.f}, {0.f, 0.f}};   // [unit][parity] fp32 state

    // gx0 double buffer (L0 epilogue threads): gxc consumed this iter (row t+1),
    // gxn loaded this iter AFTER staging loads, rotated at iter end.
    const float* gbase = g_gx0 + (size_t)eb * 1024 * 1536 + u0;
    float2 gxc[3] = {{0,0},{0,0},{0,0}};
    float2 gxn[3] = {{0,0},{0,0},{0,0}};
    if (lay == 1 && th < 128) {
        gxc[0] = *(const float2*)(gbase);            // row 0 (iter t=-1)
        gxc[1] = *(const float2*)(gbase + 512);
        gxc[2] = *(const float2*)(gbase + 1024);
    }

    unsigned long long* aW = aS + kq * 2080;         // this wave's staging block

    gridbar();   // phase-0 S visible half-wide

    // ------------------------------------------------------------- time loop
    for (int t = -1; t < 1024; ++t) {
        const unsigned short* Sc = Sbuf[(t + 1) & 1];
        unsigned short* Sn       = Sbuf[t & 1];

        // ---- stage this wave's A-quarter, COALESCED (lane = k-offset) ----
        unsigned long long tq[32];
        if (lay == 0) {
            const unsigned short* sb = Sc + bloc * 1024 + kq * 256 + (ln & 31) * 8;
            #pragma unroll
            for (int i = 0; i < 16; ++i) {
                const unsigned short* p = sb + (2 * i + (ln >> 5)) * 1024;
                tq[2 * i]     = ld64(p);
                tq[2 * i + 1] = ld64(p + 4);
            }
        } else {
            const unsigned short* sb = Sc + bloc * 1024 + kq * 128 + (ln & 15) * 8;
            #pragma unroll
            for (int i = 0; i < 8; ++i) {
                const unsigned short* p = sb + (4 * i + (ln >> 4)) * 1024;
                tq[2 * i]     = ld64(p);
                tq[2 * i + 1] = ld64(p + 4);
            }
        }
        if (lay == 1 && th < 128) {       // prefetch gx0 row t+2 (consumed next iter)
            const int tt2 = (t + 2 < 1024) ? (t + 2) : 1023;
            const float* g2 = gbase + (size_t)tt2 * 1536;
            gxn[0] = *(const float2*)(g2);
            gxn[1] = *(const float2*)(g2 + 512);
            gxn[2] = *(const float2*)(g2 + 1024);
        }
        // ---- ds_write staged quarter, DE-INTERLEAVED (conflict-free) ----
        // even ulong j -> slot j/2; odd j -> slot half + j/2 (half=32 L1, 16 L0)
        if (lay == 0) {
            #pragma unroll
            for (int i = 0; i < 16; ++i) {
                const int row = 2 * i + (ln >> 5), L = ln & 31;
                aW[row * 65 + L]      = tq[2 * i];
                aW[row * 65 + 32 + L] = tq[2 * i + 1];
            }
        } else {
            #pragma unroll
            for (int i = 0; i < 8; ++i) {
                const int row = 4 * i + (ln >> 4), L = ln & 15;
                aW[row * 33 + L]      = tq[2 * i];
                aW[row * 33 + 16 + L] = tq[2 * i + 1];
            }
        }
        // ---- MFMA chain: fragments from LDS (lane = row, 2x ds_read_b64) ----
        f32x16 acc;
        #pragma unroll
        for (int i = 0; i < 16; ++i) acc[i] = 0.0f;
        {
            const int r = ln & 31, hi = ln >> 5;
            if (lay == 0) {
                const unsigned long long* rb = aW + r * 65 + hi;
                #pragma unroll
                for (int ks = 0; ks < 16; ++ks) {
                    union { unsigned long long q[2]; bf16x8 b; } fv;
                    fv.q[0] = rb[ks * 2];
                    fv.q[1] = rb[32 + ks * 2];
                    acc = __builtin_amdgcn_mfma_f32_32x32x16_bf16(fv.b, breg[ks], acc, 0, 0, 0);
                }
            } else {
                const unsigned long long* rb = aW + r * 33 + hi;
                #pragma unroll
                for (int ks = 0; ks < 8; ++ks) {
                    union { unsigned long long q[2]; bf16x8 b; } fv;
                    fv.q[0] = rb[ks * 2];
                    fv.q[1] = rb[16 + ks * 2];
                    acc = __builtin_amdgcn_mfma_f32_32x32x16_bf16(fv.b, breg[ks], acc, 0, 0, 0);
                }
            }
        }
        {   // partials -> LDS  (C: col=lane&31, row=(r&3)+8*(r>>2)+4*(lane>>5))
            const int col = ln & 31, rbase = (ln >> 5) << 2;
            #pragma unroll
            for (int r = 0; r < 16; ++r) {
                int row = (r & 3) + ((r >> 2) << 3) + rbase;
                ldsC[(kq * 32 + row) * 33 + col] = acc[r];
            }
        }
        __syncthreads();

        if (th < 128) {   // fused gate epilogue: 2 units per thread
            float d[2][4];
            #pragma unroll
            for (int s = 0; s < 2; ++s)
                #pragma unroll
                for (int g = 0; g < 4; ++g) d[s][g] = 0.0f;
            #pragma unroll
            for (int w = 0; w < 4; ++w) {
                const float* Cw = ldsC + (w * 32 + ebl) * 33 + 2 * eq;
                #pragma unroll
                for (int s = 0; s < 2; ++s)
                    #pragma unroll
                    for (int g = 0; g < 4; ++g)
                        d[s][g] += Cw[g * 8 + s];
            }
            if (lay == 1) {       // add precomputed x-gates (r, z, n_x)
                d[0][0] += gxc[0].x; d[1][0] += gxc[0].y;
                d[0][1] += gxc[1].x; d[1][1] += gxc[1].y;
                d[0][2] += gxc[2].x; d[1][2] += gxc[2].y;
            }
            float hn[2];
            #pragma unroll
            for (int s = 0; s < 2; ++s) {
                float rg = fsig(d[s][0] + ebs[s][0]);
                float zg = fsig(d[s][1] + ebs[s][1]);
                float ng = ftanh((d[s][2] + ebs[s][2]) + rg * (d[s][3] + ebs[s][3]));
                float hold = hprev[s][(t + 1) & 1];
                hn[s] = ng + zg * (hold - ng);
            }
            if (lay == 1) {                        // layer 0 -> h0(t+1)
                hprev[0][t & 1] = hn[0]; hprev[1][t & 1] = hn[1];
                st32(Sn + eb * 1024 + u0, pack2(hn[0], hn[1]));
            } else if (t >= 0) {                   // layer 1 -> h1(t)
                hprev[0][t & 1] = hn[0]; hprev[1][t & 1] = hn[1];
                unsigned pk = pack2(hn[0], hn[1]);
                st32(Sn + eb * 1024 + 512 + u0, pk);
                // h1 history (normal cached store; visible at kernel end)
                *(unsigned int*)(g_h1 + ((unsigned)t * 64 + eb) * 512 + u0) = pk;
            }
        }
        // rotate gx0 double buffer
        gxc[0] = gxn[0]; gxc[1] = gxn[1]; gxc[2] = gxn[2];

        gridbar();
    }
}

// ---------------------------------------------------------------------------
// gx0_pre: g_gx0[65536][1536] = x[65536][256] @ Wih0^T (f32 out, bf16 MFMA).
// 512 WGs x 4 waves; wave = m-tile (32 rows); A held in regs, loops 48 n-tiles.
// ---------------------------------------------------------------------------
__global__ __launch_bounds__(256, 1)
void gx0_pre(const float* __restrict__ xin, const float* __restrict__ Wih0)
{
    const int th = threadIdx.x;
    const int ln = th & 63;
    const int v  = th >> 6;
    const int W  = blockIdx.x * 4 + v;        // m-tile [0, 2048)
    const int kh = (ln >> 5) << 3;
    const int cl = ln & 31;

    bf16x8 areg[16];
    {
        const float* xr = xin + ((size_t)W * 32 + cl) * 256 + kh;
        #pragma unroll
        for (int ks = 0; ks < 16; ++ks) {
            const float* s = xr + ks * 16;
            bf16x8 z;
            #pragma unroll
            for (int j = 0; j < 8; ++j) z[j] = (__bf16)s[j];
            areg[ks] = z;
        }
    }

    for (int nt = 0; nt < 48; ++nt) {
        f32x16 acc;
        #pragma unroll
        for (int q = 0; q < 16; ++q) acc[q] = 0.0f;
        const float* wb = Wih0 + (size_t)(nt * 32 + cl) * 256 + kh;
        #pragma unroll
        for (int ks = 0; ks < 16; ++ks) {
            const float* s = wb + ks * 16;
            bf16x8 z;
            #pragma unroll
            for (int j = 0; j < 8; ++j) z[j] = (__bf16)s[j];
            acc = __builtin_amdgcn_mfma_f32_32x32x16_bf16(areg[ks], z, acc, 0, 0, 0);
        }
        const int rb = (ln >> 5) << 2;
        #pragma unroll
        for (int r = 0; r < 16; ++r) {
            int rr = (r & 3) + ((r >> 2) << 3) + rb;
            g_gx0[((size_t)W * 32 + rr) * 1536 + nt * 32 + cl] = acc[r];
        }
    }
}

// ---------------------------------------------------------------------------
// FC pass: out[65536][256] = g_h1[65536][512] @ Wfc^T + bfc. (unchanged)
// ---------------------------------------------------------------------------
__global__ __launch_bounds__(256, 1)
void fc_out(const float* __restrict__ Wfc, const float* __restrict__ bfc,
            float* __restrict__ out)
{
    const int th = threadIdx.x;
    const int ln = th & 63;
    const int v  = th >> 6;
    const int w  = blockIdx.x * 4 + v;    // [0, 1024)
    const int ntile = w & 7;
    const int mbase = w >> 3;             // [0, 128)
    const int kh = (ln >> 5) << 3;
    const int col = ln & 31;

    bf16x8 fb[32];
    {
        const int n = ntile * 32 + col;
        #pragma unroll
        for (int ks = 0; ks < 32; ++ks) {
            const float* src = Wfc + n * 512 + ks * 16 + kh;
            bf16x8 z;
            #pragma unroll
            for (int j = 0; j < 8; ++j) z[j] = (__bf16)src[j];
            fb[ks] = z;
        }
    }
    const float bias = bfc[ntile * 32 + col];

    for (int i = 0; i < 16; ++i) {
        const int mt = mbase + i * 128;   // m-tile [0, 2048)
        const unsigned short* ar = g_h1 + ((unsigned)(mt * 32 + col)) * 512 + kh;
        f32x16 acc;
        #pragma unroll
        for (int q = 0; q < 16; ++q) acc[q] = 0.0f;
        #pragma unroll
        for (int ks = 0; ks < 32; ++ks) {
            bf16x8 af = *(const bf16x8*)(ar + ks * 16);
            acc = __builtin_amdgcn_mfma_f32_32x32x16_bf16(af, fb[ks], acc, 0, 0, 0);
        }
        const int rb = (ln >> 5) << 2;
        #pragma unroll
        for (int r = 0; r < 16; ++r) {
            int row = (r & 3) + ((r >> 2) << 3) + rb;
            out[((unsigned)(mt * 32 + row)) * 256 + ntile * 32 + col] = acc[r] + bias;
        }
    }
}

extern "C" void kernel_launch(void* const* d_in, const int* in_sizes, int n_in,
                              void* d_out, int out_size, void* d_ws, size_t ws_size,
                              hipStream_t stream) {
    (void)in_sizes; (void)n_in; (void)out_size; (void)ws_size;
    hipMemsetAsync(d_ws, 0, 4096, stream);   // barrier counters (monotonic per launch)
    const float* xin  = (const float*)d_in[0];
    const float* Wih0 = (const float*)d_in[1];
    const float* bih0 = (const float*)d_in[2];
    const float* Whh0 = (const float*)d_in[3];
    const float* bhh0 = (const float*)d_in[4];
    const float* Wih1 = (const float*)d_in[5];
    const float* bih1 = (const float*)d_in[6];
    const float* Whh1 = (const float*)d_in[7];
    const float* bhh1 = (const float*)d_in[8];
    const float* Wfc  = (const float*)d_in[9];
    const float* bfc  = (const float*)d_in[10];
    float* outp = (float*)d_out;
    unsigned int* barp = (unsigned int*)d_ws;

    hipLaunchKernelGGL(gx0_pre, dim3(512), dim3(256), 0, stream, xin, Wih0);

    void* args[] = {&xin, &Wih0, &bih0, &Whh0, &bhh0, &Wih1, &bih1,
                    &Whh1, &bhh1, &Wfc, &bfc, &outp, &barp};
    hipLaunchCooperativeKernel((void*)gru_fused, dim3(256), dim3(256),
                               args, 0, stream);
    hipLaunchKernelGGL(fc_out, dim3(256), dim3(256), 0, stream,
                       Wfc, bfc, outp);
}

// Round 11
// 5812.450 us; speedup vs baseline: 2.0489x; 1.0763x over previous
//
#include <hip/hip_runtime.h>

// ---------------------------------------------------------------------------
// GRU (2-layer, B=64, T=1024, I=256, H=512) + FC(512->256). FP32 I/O,
// bf16 MFMA internally. R14 = R12 (proven 5487 us, conflict-free staging)
// + ONE change: flag/broadcast barrier replacing the 2-level RMW tree.
//  Old: 16 fetch_adds on one line (serialize ~100-200cy each) + 8 master
//  RMWs + poll  ->  ~1+ us/step of serialized L3 RMW.
//  New (per half): arrival = plain st32 to a private 32B-spaced slot (64
//  parallel stores); master WG's wave-0 reads all 64 slots in ONE vector
//  load + __all; release = single flag store; all WGs poll that one line.
//  Zero atomics. Workspace use grows to 8.2 KB (memset 8192).
//  R11/R13's 2x consolidation: permanently reverted (bit-identical
//  deterministic failure absmax 0.311 in two different variants).
// ---------------------------------------------------------------------------

typedef __bf16 bf16x8 __attribute__((ext_vector_type(8)));
typedef float f32x16 __attribute__((ext_vector_type(16)));

// S ping-pong: [2][64 b][1024 k] bf16 (h0 | h1), fully rewritten every launch
__device__ __align__(16) unsigned short g_S[2 * 64 * 1024];
// h1 history for the FC pass: [T*B][512] bf16 = 64 MB (normal cached stores)
__device__ __align__(16) unsigned short g_h1[1024 * 64 * 512];
// gx0: [b][t][1536] f32 = 402 MB (written by gx0_pre, read by gru_fused)
__device__ __align__(16) float g_gx0[64 * 1024 * 1536];

__device__ __forceinline__ unsigned short f2b(float f) {
    unsigned u = __float_as_uint(f);
    u += 0x7fffu + ((u >> 16) & 1u);          // round to nearest even
    return (unsigned short)(u >> 16);
}
__device__ __forceinline__ unsigned int pack2(float a, float b) {
    return (unsigned)f2b(a) | ((unsigned)f2b(b) << 16);
}
// Agent-scope (cross-XCD coherent) relaxed accessors
__device__ __forceinline__ void st32(void* p, unsigned int v) {
    __hip_atomic_store((unsigned int*)p, v, __ATOMIC_RELAXED, __HIP_MEMORY_SCOPE_AGENT);
}
__device__ __forceinline__ unsigned int ld32(const void* p) {
    return __hip_atomic_load((const unsigned int*)p, __ATOMIC_RELAXED,
                             __HIP_MEMORY_SCOPE_AGENT);
}
__device__ __forceinline__ unsigned long long ld64(const void* p) {
    return __hip_atomic_load((const unsigned long long*)p, __ATOMIC_RELAXED,
                             __HIP_MEMORY_SCOPE_AGENT);
}
__device__ __forceinline__ float fsig(float x)  { return 1.0f / (1.0f + __expf(-x)); }
__device__ __forceinline__ float ftanh(float x) { return 1.0f - 2.0f / (__expf(2.0f * x) + 1.0f); }

__global__ __launch_bounds__(256, 1)
void gru_fused(const float* __restrict__ xin,   // unused (ABI)
               const float* __restrict__ Wih0, const float* __restrict__ bih0,
               const float* __restrict__ Whh0, const float* __restrict__ bhh0,
               const float* __restrict__ Wih1, const float* __restrict__ bih1,
               const float* __restrict__ Whh1, const float* __restrict__ bhh1,
               const float* __restrict__ Wfc,  const float* __restrict__ bfc,
               float* __restrict__ out, unsigned int* __restrict__ bar)
{
    (void)xin; (void)Wih0; (void)Wfc; (void)bfc; (void)out;
    // per-wave A staging: [4 waves][32 rows][65 ulong], de-interleaved slots.
    __shared__ unsigned long long aS[4 * 2080];   // 66.6 KB
    __shared__ float ldsC[4224];                  // [4 waves][32 rows][33]

    const int th = threadIdx.x;
    const int wg = blockIdx.x;            // 256 WGs (cooperative: co-resident)
    const int bh = wg >> 7;               // batch half
    const int r_ = wg & 127;
    const int lay = r_ >> 6;              // 0 = layer 1, 1 = layer 0
    const int cg  = r_ & 63;              // column group: units 8cg..8cg+7
    const int kq = th >> 6;               // wave = K-split
    const int ln = th & 63;
    const int bloc = bh * 32;

    unsigned short* Sbuf0 = g_S;                  // [64 b][1024 k] bf16
    unsigned short* Sbuf1 = g_S + 64 * 1024;
    unsigned short* Sbuf[2] = {Sbuf0, Sbuf1};

    // flag/broadcast barrier state (per half):
    //  slots: u32 at bar[bh*512 + r_*4]  (16 B spacing, 128 slots... see below)
    //  NOTE: 128 WGs per half -> 128 slots; wave-0 (64 lanes) reads 2 each.
    unsigned int* slots   = bar + bh * 512;       // slot r_ at +r_*4 (16 B)
    unsigned int* release = bar + 1024 + bh * 32; // bytes 4096 / 4224

    unsigned int gen = 0;
    auto gridbar = [&]() {
        __syncthreads();                  // drains vmcnt(0): sc1 stores at L3
        gen++;
        if (th == 0) st32(&slots[r_ * 4], gen);        // parallel arrival
        if (r_ == 0 && th < 64) {                      // master wave gathers
            for (;;) {
                unsigned a = ld32(&slots[th * 4]);
                unsigned b = ld32(&slots[(th + 64) * 4]);
                if (__all(a >= gen && b >= gen)) break;
                __builtin_amdgcn_s_sleep(1);
            }
            if (th == 0) st32(release, gen);           // broadcast release
        }
        if (th == 0) {
            while (ld32(release) < gen)
                __builtin_amdgcn_s_sleep(1);
        }
        __syncthreads();
    };

    // ---------------------------------------------------------------- phase 0
    // zero both S buffers (half-local): 2 bufs x 32 rows x 512 u32 = 32768 u32
    {
        int ltid = r_ * 256 + th;                  // [0, 32768)
        int buf = ltid >> 14, rem = ltid & 16383;
        int b = bloc + (rem >> 9), kp = rem & 511;
        st32(Sbuf[buf] + b * 1024 + kp * 2, 0u);
    }

    // ------------------------- preload B-fragments from GLOBAL (fp32 -> bf16)
    // tile = 32 cols = 4 gate types x 8 units; col nl = ty*8 + p.
    // L1 (lay=0): K=1024: [0,512)=h0 (Wih1), [512,1024)=h1 (Whh1); 16 frags.
    // L0 (lay=1): K=512: h0 (Whh0); ty==2 (n_x) zero (lives in gx0); 8 frags.
    bf16x8 breg[16];
    {
        const int nl = ln & 31, ty = nl >> 3, p = nl & 7;
        const int u = cg * 8 + p;
        const int kh = (ln >> 5) << 3;
        if (lay == 0) {
            #pragma unroll
            for (int ks = 0; ks < 16; ++ks) {
                const int k = kq * 256 + ks * 16 + kh;
                const float* src = nullptr;
                if (k < 512) {
                    if (ty != 3) src = Wih1 + (u + (ty == 1 ? 512 : (ty == 2 ? 1024 : 0))) * 512 + k;
                } else {
                    if (ty != 2) src = Whh1 + (u + (ty == 1 ? 512 : (ty == 3 ? 1024 : 0))) * 512 + (k - 512);
                }
                bf16x8 z;
                #pragma unroll
                for (int j = 0; j < 8; ++j) z[j] = (__bf16)0.0f;
                if (src) {
                    #pragma unroll
                    for (int j = 0; j < 8; ++j) z[j] = (__bf16)src[j];
                }
                breg[ks] = z;
            }
        } else {
            #pragma unroll
            for (int ks = 0; ks < 8; ++ks) {
                const int k = kq * 128 + ks * 16 + kh;     // < 512
                const float* src = nullptr;
                if (ty != 2) src = Whh0 + (u + (ty == 1 ? 512 : (ty == 3 ? 1024 : 0))) * 512 + k;
                bf16x8 z;
                #pragma unroll
                for (int j = 0; j < 8; ++j) z[j] = (__bf16)0.0f;
                if (src) {
                    #pragma unroll
                    for (int j = 0; j < 8; ++j) z[j] = (__bf16)src[j];
                }
                breg[ks] = z;
            }
        }
    }

    // -------------------- epilogue roles: 128 threads x 2 adjacent units each
    const int ebl = th & 31;              // batch row within half
    const int eq  = (th >> 5) & 3;        // unit-pair within tile
    const int u0 = cg * 8 + 2 * eq;
    const int eb = bloc + ebl;
    float ebs[2][4];
    {
        const float* bi  = lay ? bih0 : bih1;
        const float* bhp = lay ? bhh0 : bhh1;
        #pragma unroll
        for (int s = 0; s < 2; ++s) {
            int u = u0 + s;
            ebs[s][0] = bi[u]        + bhp[u];
            ebs[s][1] = bi[512 + u]  + bhp[512 + u];
            ebs[s][2] = bi[1024 + u];
            ebs[s][3] = bhp[1024 + u];
        }
    }
    float hprev[2][2] = {{0.f, 0.f}, {0.f, 0.f}};   // [unit][parity] fp32 state

    // gx0 double buffer (L0 epilogue threads): gxc consumed this iter (row t+1),
    // gxn loaded this iter AFTER staging loads, rotated at iter end.
    const float* gbase = g_gx0 + (size_t)eb * 1024 * 1536 + u0;
    float2 gxc[3] = {{0,0},{0,0},{0,0}};
    float2 gxn[3] = {{0,0},{0,0},{0,0}};
    if (lay == 1 && th < 128) {
        gxc[0] = *(const float2*)(gbase);            // row 0 (iter t=-1)
        gxc[1] = *(const float2*)(gbase + 512);
        gxc[2] = *(const float2*)(gbase + 1024);
    }

    unsigned long long* aW = aS + kq * 2080;         // this wave's staging block

    gridbar();   // phase-0 S visible half-wide

    // ------------------------------------------------------------- time loop
    for (int t = -1; t < 1024; ++t) {
        const unsigned short* Sc = Sbuf[(t + 1) & 1];
        unsigned short* Sn       = Sbuf[t & 1];

        // ---- stage this wave's A-quarter, COALESCED (lane = k-offset) ----
        unsigned long long tq[32];
        if (lay == 0) {
            const unsigned short* sb = Sc + bloc * 1024 + kq * 256 + (ln & 31) * 8;
            #pragma unroll
            for (int i = 0; i < 16; ++i) {
                const unsigned short* p = sb + (2 * i + (ln >> 5)) * 1024;
                tq[2 * i]     = ld64(p);
                tq[2 * i + 1] = ld64(p + 4);
            }
        } else {
            const unsigned short* sb = Sc + bloc * 1024 + kq * 128 + (ln & 15) * 8;
            #pragma unroll
            for (int i = 0; i < 8; ++i) {
                const unsigned short* p = sb + (4 * i + (ln >> 4)) * 1024;
                tq[2 * i]     = ld64(p);
                tq[2 * i + 1] = ld64(p + 4);
            }
        }
        if (lay == 1 && th < 128) {       // prefetch gx0 row t+2 (consumed next iter)
            const int tt2 = (t + 2 < 1024) ? (t + 2) : 1023;
            const float* g2 = gbase + (size_t)tt2 * 1536;
            gxn[0] = *(const float2*)(g2);
            gxn[1] = *(const float2*)(g2 + 512);
            gxn[2] = *(const float2*)(g2 + 1024);
        }
        // ---- ds_write staged quarter, DE-INTERLEAVED (conflict-free) ----
        // even ulong j -> slot j/2; odd j -> slot half + j/2 (half=32 L1, 16 L0)
        if (lay == 0) {
            #pragma unroll
            for (int i = 0; i < 16; ++i) {
                const int row = 2 * i + (ln >> 5), L = ln & 31;
                aW[row * 65 + L]      = tq[2 * i];
                aW[row * 65 + 32 + L] = tq[2 * i + 1];
            }
        } else {
            #pragma unroll
            for (int i = 0; i < 8; ++i) {
                const int row = 4 * i + (ln >> 4), L = ln & 15;
                aW[row * 33 + L]      = tq[2 * i];
                aW[row * 33 + 16 + L] = tq[2 * i + 1];
            }
        }
        // ---- MFMA chain: fragments from LDS (lane = row, 2x ds_read_b64) ----
        f32x16 acc;
        #pragma unroll
        for (int i = 0; i < 16; ++i) acc[i] = 0.0f;
        {
            const int r = ln & 31, hi = ln >> 5;
            if (lay == 0) {
                const unsigned long long* rb = aW + r * 65 + hi;
                #pragma unroll
                for (int ks = 0; ks < 16; ++ks) {
                    union { unsigned long long q[2]; bf16x8 b; } fv;
                    fv.q[0] = rb[ks * 2];
                    fv.q[1] = rb[32 + ks * 2];
                    acc = __builtin_amdgcn_mfma_f32_32x32x16_bf16(fv.b, breg[ks], acc, 0, 0, 0);
                }
            } else {
                const unsigned long long* rb = aW + r * 33 + hi;
                #pragma unroll
                for (int ks = 0; ks < 8; ++ks) {
                    union { unsigned long long q[2]; bf16x8 b; } fv;
                    fv.q[0] = rb[ks * 2];
                    fv.q[1] = rb[16 + ks * 2];
                    acc = __builtin_amdgcn_mfma_f32_32x32x16_bf16(fv.b, breg[ks], acc, 0, 0, 0);
                }
            }
        }
        {   // partials -> LDS  (C: col=lane&31, row=(r&3)+8*(r>>2)+4*(lane>>5))
            const int col = ln & 31, rbase = (ln >> 5) << 2;
            #pragma unroll
            for (int r = 0; r < 16; ++r) {
                int row = (r & 3) + ((r >> 2) << 3) + rbase;
                ldsC[(kq * 32 + row) * 33 + col] = acc[r];
            }
        }
        __syncthreads();

        if (th < 128) {   // fused gate epilogue: 2 units per thread
            float d[2][4];
            #pragma unroll
            for (int s = 0; s < 2; ++s)
                #pragma unroll
                for (int g = 0; g < 4; ++g) d[s][g] = 0.0f;
            #pragma unroll
            for (int w = 0; w < 4; ++w) {
                const float* Cw = ldsC + (w * 32 + ebl) * 33 + 2 * eq;
                #pragma unroll
                for (int s = 0; s < 2; ++s)
                    #pragma unroll
                    for (int g = 0; g < 4; ++g)
                        d[s][g] += Cw[g * 8 + s];
            }
            if (lay == 1) {       // add precomputed x-gates (r, z, n_x)
                d[0][0] += gxc[0].x; d[1][0] += gxc[0].y;
                d[0][1] += gxc[1].x; d[1][1] += gxc[1].y;
                d[0][2] += gxc[2].x; d[1][2] += gxc[2].y;
            }
            float hn[2];
            #pragma unroll
            for (int s = 0; s < 2; ++s) {
                float rg = fsig(d[s][0] + ebs[s][0]);
                float zg = fsig(d[s][1] + ebs[s][1]);
                float ng = ftanh((d[s][2] + ebs[s][2]) + rg * (d[s][3] + ebs[s][3]));
                float hold = hprev[s][(t + 1) & 1];
                hn[s] = ng + zg * (hold - ng);
            }
            if (lay == 1) {                        // layer 0 -> h0(t+1)
                hprev[0][t & 1] = hn[0]; hprev[1][t & 1] = hn[1];
                st32(Sn + eb * 1024 + u0, pack2(hn[0], hn[1]));
            } else if (t >= 0) {                   // layer 1 -> h1(t)
                hprev[0][t & 1] = hn[0]; hprev[1][t & 1] = hn[1];
                unsigned pk = pack2(hn[0], hn[1]);
                st32(Sn + eb * 1024 + 512 + u0, pk);
                // h1 history (normal cached store; visible at kernel end)
                *(unsigned int*)(g_h1 + ((unsigned)t * 64 + eb) * 512 + u0) = pk;
            }
        }
        // rotate gx0 double buffer
        gxc[0] = gxn[0]; gxc[1] = gxn[1]; gxc[2] = gxn[2];

        gridbar();
    }
}

// ---------------------------------------------------------------------------
// gx0_pre: g_gx0[65536][1536] = x[65536][256] @ Wih0^T (f32 out, bf16 MFMA).
// 512 WGs x 4 waves; wave = m-tile (32 rows); A held in regs, loops 48 n-tiles.
// ---------------------------------------------------------------------------
__global__ __launch_bounds__(256, 1)
void gx0_pre(const float* __restrict__ xin, const float* __restrict__ Wih0)
{
    const int th = threadIdx.x;
    const int ln = th & 63;
    const int v  = th >> 6;
    const int W  = blockIdx.x * 4 + v;        // m-tile [0, 2048)
    const int kh = (ln >> 5) << 3;
    const int cl = ln & 31;

    bf16x8 areg[16];
    {
        const float* xr = xin + ((size_t)W * 32 + cl) * 256 + kh;
        #pragma unroll
        for (int ks = 0; ks < 16; ++ks) {
            const float* s = xr + ks * 16;
            bf16x8 z;
            #pragma unroll
            for (int j = 0; j < 8; ++j) z[j] = (__bf16)s[j];
            areg[ks] = z;
        }
    }

    for (int nt = 0; nt < 48; ++nt) {
        f32x16 acc;
        #pragma unroll
        for (int q = 0; q < 16; ++q) acc[q] = 0.0f;
        const float* wb = Wih0 + (size_t)(nt * 32 + cl) * 256 + kh;
        #pragma unroll
        for (int ks = 0; ks < 16; ++ks) {
            const float* s = wb + ks * 16;
            bf16x8 z;
            #pragma unroll
            for (int j = 0; j < 8; ++j) z[j] = (__bf16)s[j];
            acc = __builtin_amdgcn_mfma_f32_32x32x16_bf16(areg[ks], z, acc, 0, 0, 0);
        }
        const int rb = (ln >> 5) << 2;
        #pragma unroll
        for (int r = 0; r < 16; ++r) {
            int rr = (r & 3) + ((r >> 2) << 3) + rb;
            g_gx0[((size_t)W * 32 + rr) * 1536 + nt * 32 + cl] = acc[r];
        }
    }
}

// ---------------------------------------------------------------------------
// FC pass: out[65536][256] = g_h1[65536][512] @ Wfc^T + bfc. (unchanged)
// ---------------------------------------------------------------------------
__global__ __launch_bounds__(256, 1)
void fc_out(const float* __restrict__ Wfc, const float* __restrict__ bfc,
            float* __restrict__ out)
{
    const int th = threadIdx.x;
    const int ln = th & 63;
    const int v  = th >> 6;
    const int w  = blockIdx.x * 4 + v;    // [0, 1024)
    const int ntile = w & 7;
    const int mbase = w >> 3;             // [0, 128)
    const int kh = (ln >> 5) << 3;
    const int col = ln & 31;

    bf16x8 fb[32];
    {
        const int n = ntile * 32 + col;
        #pragma unroll
        for (int ks = 0; ks < 32; ++ks) {
            const float* src = Wfc + n * 512 + ks * 16 + kh;
            bf16x8 z;
            #pragma unroll
            for (int j = 0; j < 8; ++j) z[j] = (__bf16)src[j];
            fb[ks] = z;
        }
    }
    const float bias = bfc[ntile * 32 + col];

    for (int i = 0; i < 16; ++i) {
        const int mt = mbase + i * 128;   // m-tile [0, 2048)
        const unsigned short* ar = g_h1 + ((unsigned)(mt * 32 + col)) * 512 + kh;
        f32x16 acc;
        #pragma unroll
        for (int q = 0; q < 16; ++q) acc[q] = 0.0f;
        #pragma unroll
        for (int ks = 0; ks < 32; ++ks) {
            bf16x8 af = *(const bf16x8*)(ar + ks * 16);
            acc = __builtin_amdgcn_mfma_f32_32x32x16_bf16(af, fb[ks], acc, 0, 0, 0);
        }
        const int rb = (ln >> 5) << 2;
        #pragma unroll
        for (int r = 0; r < 16; ++r) {
            int row = (r & 3) + ((r >> 2) << 3) + rb;
            out[((unsigned)(mt * 32 + row)) * 256 + ntile * 32 + col] = acc[r] + bias;
        }
    }
}

extern "C" void kernel_launch(void* const* d_in, const int* in_sizes, int n_in,
                              void* d_out, int out_size, void* d_ws, size_t ws_size,
                              hipStream_t stream) {
    (void)in_sizes; (void)n_in; (void)out_size; (void)ws_size;
    hipMemsetAsync(d_ws, 0, 8192, stream);   // barrier slots + release flags
    const float* xin  = (const float*)d_in[0];
    const float* Wih0 = (const float*)d_in[1];
    const float* bih0 = (const float*)d_in[2];
    const float* Whh0 = (const float*)d_in[3];
    const float* bhh0 = (const float*)d_in[4];
    const float* Wih1 = (const float*)d_in[5];
    const float* bih1 = (const float*)d_in[6];
    const float* Whh1 = (const float*)d_in[7];
    const float* bhh1 = (const float*)d_in[8];
    const float* Wfc  = (const float*)d_in[9];
    const float* bfc  = (const float*)d_in[10];
    float* outp = (float*)d_out;
    unsigned int* barp = (unsigned int*)d_ws;

    hipLaunchKernelGGL(gx0_pre, dim3(512), dim3(256), 0, stream, xin, Wih0);

    void* args[] = {&xin, &Wih0, &bih0, &Whh0, &bhh0, &Wih1, &bih1,
                    &Whh1, &bhh1, &Wfc, &bfc, &outp, &barp};
    hipLaunchCooperativeKernel((void*)gru_fused, dim3(256), dim3(256),
                               args, 0, stream);
    hipLaunchKernelGGL(fc_out, dim3(256), dim3(256), 0, stream,
                       Wfc, bfc, outp);
}

// Round 13
// 4874.605 us; speedup vs baseline: 2.4431x; 1.1924x over previous
//
#include <hip/hip_runtime.h>

// ---------------------------------------------------------------------------
// GRU (2-layer, B=64, T=1024, I=256, H=512) + FC(512->256). FP32 I/O,
// bf16 MFMA internally. R15 = R14 (4925 us, flag/broadcast barrier) + ONE
// change: staging loads via inline-asm global_load_dwordx4 sc0 sc1 (16B/lane,
// coherent) instead of 2x 8B atomic ld64 -> per-wave staging requests halve
// (L1 32->16, L0 16->8). Manual s_waitcnt vmcnt(0) + sched_barrier(0) before
// ds_writes (asm-output-register hazard); gx0 prefetch issued AFTER the
// waitcnt so its HBM miss never extends the staging drain.
// Theory: remaining 4.8 us/step ~= serial chain (~2 us) + L3 broadcast
// population (~1-1.5 us) + stragglers; this tests the request-count term.
// (Resubmitted: R12 broker timeout, never measured.)
// ---------------------------------------------------------------------------

typedef __bf16 bf16x8 __attribute__((ext_vector_type(8)));
typedef float f32x16 __attribute__((ext_vector_type(16)));
typedef int   int4v  __attribute__((ext_vector_type(4)));

// S ping-pong: [2][64 b][1024 k] bf16 (h0 | h1), fully rewritten every launch
__device__ __align__(16) unsigned short g_S[2 * 64 * 1024];
// h1 history for the FC pass: [T*B][512] bf16 = 64 MB (normal cached stores)
__device__ __align__(16) unsigned short g_h1[1024 * 64 * 512];
// gx0: [b][t][1536] f32 = 402 MB (written by gx0_pre, read by gru_fused)
__device__ __align__(16) float g_gx0[64 * 1024 * 1536];

__device__ __forceinline__ unsigned short f2b(float f) {
    unsigned u = __float_as_uint(f);
    u += 0x7fffu + ((u >> 16) & 1u);          // round to nearest even
    return (unsigned short)(u >> 16);
}
__device__ __forceinline__ unsigned int pack2(float a, float b) {
    return (unsigned)f2b(a) | ((unsigned)f2b(b) << 16);
}
// Agent-scope (cross-XCD coherent) relaxed accessors
__device__ __forceinline__ void st32(void* p, unsigned int v) {
    __hip_atomic_store((unsigned int*)p, v, __ATOMIC_RELAXED, __HIP_MEMORY_SCOPE_AGENT);
}
__device__ __forceinline__ unsigned int ld32(const void* p) {
    return __hip_atomic_load((const unsigned int*)p, __ATOMIC_RELAXED,
                             __HIP_MEMORY_SCOPE_AGENT);
}
__device__ __forceinline__ unsigned long long ld64(const void* p) {
    return __hip_atomic_load((const unsigned long long*)p, __ATOMIC_RELAXED,
                             __HIP_MEMORY_SCOPE_AGENT);
}
// 16B coherent load (bypass L1/L2 -> L3 coherence point), manual waitcnt!
__device__ __forceinline__ int4v ld128cc(const void* p) {
    int4v r;
    asm volatile("global_load_dwordx4 %0, %1, off sc0 sc1"
                 : "=v"(r) : "v"(p));
    return r;
}
__device__ __forceinline__ float fsig(float x)  { return 1.0f / (1.0f + __expf(-x)); }
__device__ __forceinline__ float ftanh(float x) { return 1.0f - 2.0f / (__expf(2.0f * x) + 1.0f); }

__global__ __launch_bounds__(256, 1)
void gru_fused(const float* __restrict__ xin,   // unused (ABI)
               const float* __restrict__ Wih0, const float* __restrict__ bih0,
               const float* __restrict__ Whh0, const float* __restrict__ bhh0,
               const float* __restrict__ Wih1, const float* __restrict__ bih1,
               const float* __restrict__ Whh1, const float* __restrict__ bhh1,
               const float* __restrict__ Wfc,  const float* __restrict__ bfc,
               float* __restrict__ out, unsigned int* __restrict__ bar)
{
    (void)xin; (void)Wih0; (void)Wfc; (void)bfc; (void)out;
    // per-wave A staging: [4 waves][32 rows][65 ulong], de-interleaved slots.
    __shared__ unsigned long long aS[4 * 2080];   // 66.6 KB
    __shared__ float ldsC[4224];                  // [4 waves][32 rows][33]

    const int th = threadIdx.x;
    const int wg = blockIdx.x;            // 256 WGs (cooperative: co-resident)
    const int bh = wg >> 7;               // batch half
    const int r_ = wg & 127;
    const int lay = r_ >> 6;              // 0 = layer 1, 1 = layer 0
    const int cg  = r_ & 63;              // column group: units 8cg..8cg+7
    const int kq = th >> 6;               // wave = K-split
    const int ln = th & 63;
    const int bloc = bh * 32;

    unsigned short* Sbuf0 = g_S;                  // [64 b][1024 k] bf16
    unsigned short* Sbuf1 = g_S + 64 * 1024;
    unsigned short* Sbuf[2] = {Sbuf0, Sbuf1};

    // flag/broadcast barrier state (per half): 128 slots (16 B apart) + flag
    unsigned int* slots   = bar + bh * 512;       // slot r_ at +r_*4
    unsigned int* release = bar + 1024 + bh * 32;

    unsigned int gen = 0;
    auto gridbar = [&]() {
        __syncthreads();                  // drains vmcnt(0): sc1 stores at L3
        gen++;
        if (th == 0) st32(&slots[r_ * 4], gen);        // parallel arrival
        if (r_ == 0 && th < 64) {                      // master wave gathers
            for (;;) {
                unsigned a = ld32(&slots[th * 4]);
                unsigned b = ld32(&slots[(th + 64) * 4]);
                if (__all(a >= gen && b >= gen)) break;
                __builtin_amdgcn_s_sleep(1);
            }
            if (th == 0) st32(release, gen);           // broadcast release
        }
        if (th == 0) {
            while (ld32(release) < gen)
                __builtin_amdgcn_s_sleep(1);
        }
        __syncthreads();
    };

    // ---------------------------------------------------------------- phase 0
    // zero both S buffers (half-local): 2 bufs x 32 rows x 512 u32 = 32768 u32
    {
        int ltid = r_ * 256 + th;                  // [0, 32768)
        int buf = ltid >> 14, rem = ltid & 16383;
        int b = bloc + (rem >> 9), kp = rem & 511;
        st32(Sbuf[buf] + b * 1024 + kp * 2, 0u);
    }

    // ------------------------- preload B-fragments from GLOBAL (fp32 -> bf16)
    // tile = 32 cols = 4 gate types x 8 units; col nl = ty*8 + p.
    // L1 (lay=0): K=1024: [0,512)=h0 (Wih1), [512,1024)=h1 (Whh1); 16 frags.
    // L0 (lay=1): K=512: h0 (Whh0); ty==2 (n_x) zero (lives in gx0); 8 frags.
    bf16x8 breg[16];
    {
        const int nl = ln & 31, ty = nl >> 3, p = nl & 7;
        const int u = cg * 8 + p;
        const int kh = (ln >> 5) << 3;
        if (lay == 0) {
            #pragma unroll
            for (int ks = 0; ks < 16; ++ks) {
                const int k = kq * 256 + ks * 16 + kh;
                const float* src = nullptr;
                if (k < 512) {
                    if (ty != 3) src = Wih1 + (u + (ty == 1 ? 512 : (ty == 2 ? 1024 : 0))) * 512 + k;
                } else {
                    if (ty != 2) src = Whh1 + (u + (ty == 1 ? 512 : (ty == 3 ? 1024 : 0))) * 512 + (k - 512);
                }
                bf16x8 z;
                #pragma unroll
                for (int j = 0; j < 8; ++j) z[j] = (__bf16)0.0f;
                if (src) {
                    #pragma unroll
                    for (int j = 0; j < 8; ++j) z[j] = (__bf16)src[j];
                }
                breg[ks] = z;
            }
        } else {
            #pragma unroll
            for (int ks = 0; ks < 8; ++ks) {
                const int k = kq * 128 + ks * 16 + kh;     // < 512
                const float* src = nullptr;
                if (ty != 2) src = Whh0 + (u + (ty == 1 ? 512 : (ty == 3 ? 1024 : 0))) * 512 + k;
                bf16x8 z;
                #pragma unroll
                for (int j = 0; j < 8; ++j) z[j] = (__bf16)0.0f;
                if (src) {
                    #pragma unroll
                    for (int j = 0; j < 8; ++j) z[j] = (__bf16)src[j];
                }
                breg[ks] = z;
            }
        }
    }

    // -------------------- epilogue roles: 128 threads x 2 adjacent units each
    const int ebl = th & 31;              // batch row within half
    const int eq  = (th >> 5) & 3;        // unit-pair within tile
    const int u0 = cg * 8 + 2 * eq;
    const int eb = bloc + ebl;
    float ebs[2][4];
    {
        const float* bi  = lay ? bih0 : bih1;
        const float* bhp = lay ? bhh0 : bhh1;
        #pragma unroll
        for (int s = 0; s < 2; ++s) {
            int u = u0 + s;
            ebs[s][0] = bi[u]        + bhp[u];
            ebs[s][1] = bi[512 + u]  + bhp[512 + u];
            ebs[s][2] = bi[1024 + u];
            ebs[s][3] = bhp[1024 + u];
        }
    }
    float hprev[2][2] = {{0.f, 0.f}, {0.f, 0.f}};   // [unit][parity] fp32 state

    // gx0 double buffer (L0 epilogue threads): gxc consumed this iter (row t+1),
    // gxn loaded this iter AFTER the staging waitcnt, rotated at iter end.
    const float* gbase = g_gx0 + (size_t)eb * 1024 * 1536 + u0;
    float2 gxc[3] = {{0,0},{0,0},{0,0}};
    float2 gxn[3] = {{0,0},{0,0},{0,0}};
    if (lay == 1 && th < 128) {
        gxc[0] = *(const float2*)(gbase);            // row 0 (iter t=-1)
        gxc[1] = *(const float2*)(gbase + 512);
        gxc[2] = *(const float2*)(gbase + 1024);
    }

    unsigned long long* aW = aS + kq * 2080;         // this wave's staging block

    gridbar();   // phase-0 S visible half-wide

    // ------------------------------------------------------------- time loop
    for (int t = -1; t < 1024; ++t) {
        const unsigned short* Sc = Sbuf[(t + 1) & 1];
        unsigned short* Sn       = Sbuf[t & 1];

        // ---- stage this wave's A-quarter: 16B coherent dwordx4 per lane ----
        union { int4v v; unsigned long long u[2]; } q[16];
        if (lay == 0) {
            const unsigned short* sb = Sc + bloc * 1024 + kq * 256 + (ln & 31) * 8;
            #pragma unroll
            for (int i = 0; i < 16; ++i)
                q[i].v = ld128cc(sb + (2 * i + (ln >> 5)) * 1024);
        } else {
            const unsigned short* sb = Sc + bloc * 1024 + kq * 128 + (ln & 15) * 8;
            #pragma unroll
            for (int i = 0; i < 8; ++i)
                q[i].v = ld128cc(sb + (4 * i + (ln >> 4)) * 1024);
        }
        asm volatile("s_waitcnt vmcnt(0)" ::: "memory");
        __builtin_amdgcn_sched_barrier(0);

        if (lay == 1 && th < 128) {       // prefetch gx0 row t+2 (consumed next iter)
            const int tt2 = (t + 2 < 1024) ? (t + 2) : 1023;
            const float* g2 = gbase + (size_t)tt2 * 1536;
            gxn[0] = *(const float2*)(g2);
            gxn[1] = *(const float2*)(g2 + 512);
            gxn[2] = *(const float2*)(g2 + 1024);
        }
        // ---- ds_write staged quarter, DE-INTERLEAVED (conflict-free) ----
        // even ulong j -> slot j/2; odd j -> slot half + j/2 (half=32 L1, 16 L0)
        if (lay == 0) {
            #pragma unroll
            for (int i = 0; i < 16; ++i) {
                const int row = 2 * i + (ln >> 5), L = ln & 31;
                aW[row * 65 + L]      = q[i].u[0];
                aW[row * 65 + 32 + L] = q[i].u[1];
            }
        } else {
            #pragma unroll
            for (int i = 0; i < 8; ++i) {
                const int row = 4 * i + (ln >> 4), L = ln & 15;
                aW[row * 33 + L]      = q[i].u[0];
                aW[row * 33 + 16 + L] = q[i].u[1];
            }
        }
        // ---- MFMA chain: fragments from LDS (lane = row, 2x ds_read_b64) ----
        f32x16 acc;
        #pragma unroll
        for (int i = 0; i < 16; ++i) acc[i] = 0.0f;
        {
            const int r = ln & 31, hi = ln >> 5;
            if (lay == 0) {
                const unsigned long long* rb = aW + r * 65 + hi;
                #pragma unroll
                for (int ks = 0; ks < 16; ++ks) {
                    union { unsigned long long qq[2]; bf16x8 b; } fv;
                    fv.qq[0] = rb[ks * 2];
                    fv.qq[1] = rb[32 + ks * 2];
                    acc = __builtin_amdgcn_mfma_f32_32x32x16_bf16(fv.b, breg[ks], acc, 0, 0, 0);
                }
            } else {
                const unsigned long long* rb = aW + r * 33 + hi;
                #pragma unroll
                for (int ks = 0; ks < 8; ++ks) {
                    union { unsigned long long qq[2]; bf16x8 b; } fv;
                    fv.qq[0] = rb[ks * 2];
                    fv.qq[1] = rb[16 + ks * 2];
                    acc = __builtin_amdgcn_mfma_f32_32x32x16_bf16(fv.b, breg[ks], acc, 0, 0, 0);
                }
            }
        }
        {   // partials -> LDS  (C: col=lane&31, row=(r&3)+8*(r>>2)+4*(lane>>5))
            const int col = ln & 31, rbase = (ln >> 5) << 2;
            #pragma unroll
            for (int r = 0; r < 16; ++r) {
                int row = (r & 3) + ((r >> 2) << 3) + rbase;
                ldsC[(kq * 32 + row) * 33 + col] = acc[r];
            }
        }
        __syncthreads();

        if (th < 128) {   // fused gate epilogue: 2 units per thread
            float d[2][4];
            #pragma unroll
            for (int s = 0; s < 2; ++s)
                #pragma unroll
                for (int g = 0; g < 4; ++g) d[s][g] = 0.0f;
            #pragma unroll
            for (int w = 0; w < 4; ++w) {
                const float* Cw = ldsC + (w * 32 + ebl) * 33 + 2 * eq;
                #pragma unroll
                for (int s = 0; s < 2; ++s)
                    #pragma unroll
                    for (int g = 0; g < 4; ++g)
                        d[s][g] += Cw[g * 8 + s];
            }
            if (lay == 1) {       // add precomputed x-gates (r, z, n_x)
                d[0][0] += gxc[0].x; d[1][0] += gxc[0].y;
                d[0][1] += gxc[1].x; d[1][1] += gxc[1].y;
                d[0][2] += gxc[2].x; d[1][2] += gxc[2].y;
            }
            float hn[2];
            #pragma unroll
            for (int s = 0; s < 2; ++s) {
                float rg = fsig(d[s][0] + ebs[s][0]);
                float zg = fsig(d[s][1] + ebs[s][1]);
                float ng = ftanh((d[s][2] + ebs[s][2]) + rg * (d[s][3] + ebs[s][3]));
                float hold = hprev[s][(t + 1) & 1];
                hn[s] = ng + zg * (hold - ng);
            }
            if (lay == 1) {                        // layer 0 -> h0(t+1)
                hprev[0][t & 1] = hn[0]; hprev[1][t & 1] = hn[1];
                st32(Sn + eb * 1024 + u0, pack2(hn[0], hn[1]));
            } else if (t >= 0) {                   // layer 1 -> h1(t)
                hprev[0][t & 1] = hn[0]; hprev[1][t & 1] = hn[1];
                unsigned pk = pack2(hn[0], hn[1]);
                st32(Sn + eb * 1024 + 512 + u0, pk);
                // h1 history (normal cached store; visible at kernel end)
                *(unsigned int*)(g_h1 + ((unsigned)t * 64 + eb) * 512 + u0) = pk;
            }
        }
        // rotate gx0 double buffer
        gxc[0] = gxn[0]; gxc[1] = gxn[1]; gxc[2] = gxn[2];

        gridbar();
    }
}

// ---------------------------------------------------------------------------
// gx0_pre: g_gx0[65536][1536] = x[65536][256] @ Wih0^T (f32 out, bf16 MFMA).
// 512 WGs x 4 waves; wave = m-tile (32 rows); A held in regs, loops 48 n-tiles.
// ---------------------------------------------------------------------------
__global__ __launch_bounds__(256, 1)
void gx0_pre(const float* __restrict__ xin, const float* __restrict__ Wih0)
{
    const int th = threadIdx.x;
    const int ln = th & 63;
    const int v  = th >> 6;
    const int W  = blockIdx.x * 4 + v;        // m-tile [0, 2048)
    const int kh = (ln >> 5) << 3;
    const int cl = ln & 31;

    bf16x8 areg[16];
    {
        const float* xr = xin + ((size_t)W * 32 + cl) * 256 + kh;
        #pragma unroll
        for (int ks = 0; ks < 16; ++ks) {
            const float* s = xr + ks * 16;
            bf16x8 z;
            #pragma unroll
            for (int j = 0; j < 8; ++j) z[j] = (__bf16)s[j];
            areg[ks] = z;
        }
    }

    for (int nt = 0; nt < 48; ++nt) {
        f32x16 acc;
        #pragma unroll
        for (int q = 0; q < 16; ++q) acc[q] = 0.0f;
        const float* wb = Wih0 + (size_t)(nt * 32 + cl) * 256 + kh;
        #pragma unroll
        for (int ks = 0; ks < 16; ++ks) {
            const float* s = wb + ks * 16;
            bf16x8 z;
            #pragma unroll
            for (int j = 0; j < 8; ++j) z[j] = (__bf16)s[j];
            acc = __builtin_amdgcn_mfma_f32_32x32x16_bf16(areg[ks], z, acc, 0, 0, 0);
        }
        const int rb = (ln >> 5) << 2;
        #pragma unroll
        for (int r = 0; r < 16; ++r) {
            int rr = (r & 3) + ((r >> 2) << 3) + rb;
            g_gx0[((size_t)W * 32 + rr) * 1536 + nt * 32 + cl] = acc[r];
        }
    }
}

// ---------------------------------------------------------------------------
// FC pass: out[65536][256] = g_h1[65536][512] @ Wfc^T + bfc. (unchanged)
// ---------------------------------------------------------------------------
__global__ __launch_bounds__(256, 1)
void fc_out(const float* __restrict__ Wfc, const float* __restrict__ bfc,
            float* __restrict__ out)
{
    const int th = threadIdx.x;
    const int ln = th & 63;
    const int v  = th >> 6;
    const int w  = blockIdx.x * 4 + v;    // [0, 1024)
    const int ntile = w & 7;
    const int mbase = w >> 3;             // [0, 128)
    const int kh = (ln >> 5) << 3;
    const int col = ln & 31;

    bf16x8 fb[32];
    {
        const int n = ntile * 32 + col;
        #pragma unroll
        for (int ks = 0; ks < 32; ++ks) {
            const float* src = Wfc + n * 512 + ks * 16 + kh;
            bf16x8 z;
            #pragma unroll
            for (int j = 0; j < 8; ++j) z[j] = (__bf16)src[j];
            fb[ks] = z;
        }
    }
    const float bias = bfc[ntile * 32 + col];

    for (int i = 0; i < 16; ++i) {
        const int mt = mbase + i * 128;   // m-tile [0, 2048)
        const unsigned short* ar = g_h1 + ((unsigned)(mt * 32 + col)) * 512 + kh;
        f32x16 acc;
        #pragma unroll
        for (int q = 0; q < 16; ++q) acc[q] = 0.0f;
        #pragma unroll
        for (int ks = 0; ks < 32; ++ks) {
            bf16x8 af = *(const bf16x8*)(ar + ks * 16);
            acc = __builtin_amdgcn_mfma_f32_32x32x16_bf16(af, fb[ks], acc, 0, 0, 0);
        }
        const int rb = (ln >> 5) << 2;
        #pragma unroll
        for (int r = 0; r < 16; ++r) {
            int row = (r & 3) + ((r >> 2) << 3) + rb;
            out[((unsigned)(mt * 32 + row)) * 256 + ntile * 32 + col] = acc[r] + bias;
        }
    }
}

extern "C" void kernel_launch(void* const* d_in, const int* in_sizes, int n_in,
                              void* d_out, int out_size, void* d_ws, size_t ws_size,
                              hipStream_t stream) {
    (void)in_sizes; (void)n_in; (void)out_size; (void)ws_size;
    hipMemsetAsync(d_ws, 0, 8192, stream);   // barrier slots + release flags
    const float* xin  = (const float*)d_in[0];
    const float* Wih0 = (const float*)d_in[1];
    const float* bih0 = (const float*)d_in[2];
    const float* Whh0 = (const float*)d_in[3];
    const float* bhh0 = (const float*)d_in[4];
    const float* Wih1 = (const float*)d_in[5];
    const float* bih1 = (const float*)d_in[6];
    const float* Whh1 = (const float*)d_in[7];
    const float* bhh1 = (const float*)d_in[8];
    const float* Wfc  = (const float*)d_in[9];
    const float* bfc  = (const float*)d_in[10];
    float* outp = (float*)d_out;
    unsigned int* barp = (unsigned int*)d_ws;

    hipLaunchKernelGGL(gx0_pre, dim3(512), dim3(256), 0, stream, xin, Wih0);

    void* args[] = {&xin, &Wih0, &bih0, &Whh0, &bhh0, &Wih1, &bih1,
                    &Whh1, &bhh1, &Wfc, &bfc, &outp, &barp};
    hipLaunchCooperativeKernel((void*)gru_fused, dim3(256), dim3(256),
                               args, 0, stream);
    hipLaunchKernelGGL(fc_out, dim3(256), dim3(256), 0, stream,
                       Wfc, bfc, outp);
}